// Round 10
// baseline (431.147 us; speedup 1.0000x reference)
//
#include <hip/hip_runtime.h>

#define NND 32768      // total nodes N = B*NNODES
#define NE  262144     // edges
#define HD 128
#define NPAIR 2048     // B*FEAS
#define NBLK 256       // mgemm blocks (NND/128)

typedef __attribute__((ext_vector_type(8))) short short8;
typedef __attribute__((ext_vector_type(4))) float f32x4;

__device__ __forceinline__ void fma4(float4& a, float s, const float4& w){
  a.x = fmaf(s, w.x, a.x);
  a.y = fmaf(s, w.y, a.y);
  a.z = fmaf(s, w.z, a.z);
  a.w = fmaf(s, w.w, a.w);
}

__device__ __forceinline__ unsigned short bf16rne(float x){
  unsigned int u = __float_as_uint(x);
  unsigned int r = u + 0x7FFFu + ((u >> 16) & 1u);
  return (unsigned short)(r >> 16);
}
__device__ __forceinline__ float bf16tof(unsigned short h){
  return __uint_as_float(((unsigned int)h) << 16);
}

// ---------------- init: zero d_out (blocks 0..2047) + wsplit (2048..2103) + zero meta (2104..2111) ----------------
__global__ __launch_bounds__(256) void k_init(float4* __restrict__ out4, int n4,
                                              float4* __restrict__ meta4, int m4,
                                              const float* __restrict__ g0w2, const float* __restrict__ gw1,
                                              const float* __restrict__ gw2, unsigned short* __restrict__ WThi,
                                              unsigned short* __restrict__ WTlo){
  __shared__ float tile[16*129];
  int bid = blockIdx.x;
  int t = threadIdx.x;
  if (bid < 2048){
    float4 z = make_float4(0.f,0.f,0.f,0.f);
    for (int i = bid*256 + t; i < n4; i += 2048*256) out4[i] = z;
  } else if (bid < 2104){
    int q = bid - 2048;
    int mat = q >> 3, kblk = q & 7;
    int k0 = kblk * 16;
    const float* W = (mat == 0) ? g0w2 : ((mat < 4) ? (gw1 + (mat-1)*16384) : (gw2 + (mat-4)*16384));
    {
      int kk = t >> 4, n0 = (t & 15) * 8;
      float4 v0 = *(const float4*)&W[(size_t)(k0+kk)*HD + n0];
      float4 v1 = *(const float4*)&W[(size_t)(k0+kk)*HD + n0 + 4];
      tile[kk*129 + n0+0] = v0.x; tile[kk*129 + n0+1] = v0.y;
      tile[kk*129 + n0+2] = v0.z; tile[kk*129 + n0+3] = v0.w;
      tile[kk*129 + n0+4] = v1.x; tile[kk*129 + n0+5] = v1.y;
      tile[kk*129 + n0+6] = v1.z; tile[kk*129 + n0+7] = v1.w;
    }
    __syncthreads();
    int n = t >> 1, koff = (t & 1) * 8;
    short8 hv, lv;
    #pragma unroll
    for (int q2=0;q2<8;q2++){
      float v = tile[(koff+q2)*129 + n];
      unsigned short h = bf16rne(v);
      hv[q2] = (short)h;
      lv[q2] = (short)bf16rne(v - bf16tof(h));
    }
    size_t o = (size_t)mat*16384 + (size_t)n*HD + k0 + koff;
    *(short8*)&WThi[o] = hv;
    *(short8*)&WTlo[o] = lv;
  } else {
    float4 z = make_float4(0.f,0.f,0.f,0.f);
    for (int i = (bid-2104)*256 + t; i < m4; i += 8*256) meta4[i] = z;
  }
}

// ---------------- CSR build ----------------
__global__ __launch_bounds__(256) void k_count(const int* __restrict__ dst, int* __restrict__ cnt){
  int e = blockIdx.x*256 + threadIdx.x;
  if (e < NE) atomicAdd(&cnt[dst[e]], 1);
}

__global__ __launch_bounds__(1024) void k_scan(const int* __restrict__ cnt, int* __restrict__ rowp,
                                               float* __restrict__ invdeg){
  __shared__ int part[1024];
  int t = threadIdx.x;
  int base = t*32;
  int local[32];
  int s = 0;
  #pragma unroll
  for (int j=0;j<32;j++){ local[j] = s; s += cnt[base+j]; }
  part[t] = s;
  __syncthreads();
  for (int d=1; d<1024; d<<=1){
    int v = (t>=d) ? part[t-d] : 0;
    __syncthreads();
    part[t] += v;
    __syncthreads();
  }
  int off = (t==0) ? 0 : part[t-1];
  #pragma unroll
  for (int j=0;j<32;j++){
    rowp[base+j] = off + local[j];
    int c = cnt[base+j];
    invdeg[base+j] = 1.0f / (float)(c > 0 ? c : 1);
  }
  if (t == 1023) rowp[NND] = off + s;
}

__global__ __launch_bounds__(256) void k_fill(const int* __restrict__ src, const int* __restrict__ dst,
                                              const int* __restrict__ rowp, int* __restrict__ fillc,
                                              int* __restrict__ csr){
  int e = blockIdx.x*256 + threadIdx.x;
  if (e < NE){
    int d = dst[e];
    int p = atomicAdd(&fillc[d], 1);
    csr[rowp[d] + p] = src[e];
  }
}

// ---------------- layer 0: fused agg(IN=8) + [Nx8]@[8x128] + bias + ReLU -> bf16 hi/lo ----------------
__global__ __launch_bounds__(256) void k_l0(const float* __restrict__ x, const int* __restrict__ rowp,
                                            const int* __restrict__ csr, const float* __restrict__ invdeg,
                                            const float* __restrict__ W, const float* __restrict__ bias,
                                            unsigned short* __restrict__ Ch, unsigned short* __restrict__ Cl){
  __shared__ float Ws[8*HD];
  __shared__ float bs[HD];
  __shared__ float zs[2*9];
  int tid = threadIdx.x;
  for (int u=tid; u<8*HD; u+=256) Ws[u] = W[u];
  if (tid < HD) bs[tid] = bias[tid];
  if (tid < 16){
    int lr = tid >> 3, f = tid & 7;
    int i = blockIdx.x*2 + lr;
    int a = rowp[i], bnd = rowp[i+1];
    float s = 0.f;
    for (int k=a;k<bnd;k++) s += x[(size_t)csr[k]*8 + f];
    zs[lr*9 + f] = x[(size_t)i*8 + f] + s*invdeg[i];
  }
  __syncthreads();
  int lr = tid >> 7, c = tid & 127;
  float s = bs[c];
  #pragma unroll
  for (int k=0;k<8;k++) s = fmaf(zs[lr*9+k], Ws[k*128+c], s);
  s = fmaxf(s, 0.f);
  unsigned short h = bf16rne(s);
  size_t g = (size_t)(blockIdx.x*2+lr)*HD + c;
  Ch[g] = h;
  Cl[g] = bf16rne(s - bf16tof(h));
}

// ---------------- MFMA GEMM: bf16x3 error-compensated (proven R8 structure) ----------------
// STATS=1: fp32 out + atomic BN sums (bnsum/bnsq) + per-batch raw colsums (gsumL slot).
// STATS=0: bf16 hi/lo out.
template<int STATS>
__global__ __launch_bounds__(256) void k_mgemm(const unsigned short* __restrict__ Ah, const unsigned short* __restrict__ Al,
                                               const unsigned short* __restrict__ Wh, const unsigned short* __restrict__ Wl,
                                               const float* __restrict__ bias, float* __restrict__ Cf,
                                               unsigned short* __restrict__ Ch, unsigned short* __restrict__ Cl,
                                               float* __restrict__ bnsum, float* __restrict__ bnsq,
                                               float* __restrict__ gsumL){
  __shared__ unsigned short AH[128*40], AL[128*40], WH[128*40], WL[128*40];  // stride 40 bf16: 2-way banks (free)
  __shared__ float SS[256], SQ[256];
  int tid = threadIdx.x;
  int r0 = blockIdx.x * 128;
  int row = tid >> 1, half = tid & 1;
  int l = tid & 63, w = tid >> 6;
  int lane15 = l & 15, lgrp = l >> 4;
  int rw = (w >> 1) * 64, cw = (w & 1) * 64;

  f32x4 acc[4][4];
  #pragma unroll
  for (int i=0;i<4;i++)
    #pragma unroll
    for (int j=0;j<4;j++){ f32x4 z = {0.f,0.f,0.f,0.f}; acc[i][j] = z; }

  size_t abase = (size_t)(r0 + row)*HD + half*16;
  size_t wbase = (size_t)row*HD + half*16;
  float4 p0 = *(const float4*)&Ah[abase];     float4 p1 = *(const float4*)&Ah[abase+8];
  float4 p2 = *(const float4*)&Al[abase];     float4 p3 = *(const float4*)&Al[abase+8];
  float4 p4 = *(const float4*)&Wh[wbase];     float4 p5 = *(const float4*)&Wh[wbase+8];
  float4 p6 = *(const float4*)&Wl[wbase];     float4 p7 = *(const float4*)&Wl[wbase+8];

  for (int k0 = 0; k0 < 128; k0 += 32){
    __syncthreads();
    int ldst = row*40 + half*16;
    *(float4*)&AH[ldst] = p0; *(float4*)&AH[ldst+8] = p1;
    *(float4*)&AL[ldst] = p2; *(float4*)&AL[ldst+8] = p3;
    *(float4*)&WH[ldst] = p4; *(float4*)&WH[ldst+8] = p5;
    *(float4*)&WL[ldst] = p6; *(float4*)&WL[ldst+8] = p7;
    __syncthreads();
    if (k0 < 96){
      p0 = *(const float4*)&Ah[abase + k0+32]; p1 = *(const float4*)&Ah[abase + k0+40];
      p2 = *(const float4*)&Al[abase + k0+32]; p3 = *(const float4*)&Al[abase + k0+40];
      p4 = *(const float4*)&Wh[wbase + k0+32]; p5 = *(const float4*)&Wh[wbase + k0+40];
      p6 = *(const float4*)&Wl[wbase + k0+32]; p7 = *(const float4*)&Wl[wbase + k0+40];
    }
    short8 ah[4], al[4], wh[4], wl[4];
    #pragma unroll
    for (int i=0;i<4;i++){
      int ar = (rw + 16*i + lane15)*40 + lgrp*8;
      ah[i] = *(const short8*)&AH[ar];
      al[i] = *(const short8*)&AL[ar];
      int wr = (cw + 16*i + lane15)*40 + lgrp*8;
      wh[i] = *(const short8*)&WH[wr];
      wl[i] = *(const short8*)&WL[wr];
    }
    #pragma unroll
    for (int i=0;i<4;i++){
      #pragma unroll
      for (int j=0;j<4;j++){
        acc[i][j] = __builtin_amdgcn_mfma_f32_16x16x32_bf16(ah[i], wh[j], acc[i][j], 0, 0, 0);
        acc[i][j] = __builtin_amdgcn_mfma_f32_16x16x32_bf16(al[i], wh[j], acc[i][j], 0, 0, 0);
        acc[i][j] = __builtin_amdgcn_mfma_f32_16x16x32_bf16(ah[i], wl[j], acc[i][j], 0, 0, 0);
      }
    }
  }

  float bj[4], sj[4] = {0,0,0,0}, qj[4] = {0,0,0,0};
  #pragma unroll
  for (int j=0;j<4;j++) bj[j] = bias[cw + 16*j + lane15];
  #pragma unroll
  for (int i=0;i<4;i++){
    #pragma unroll
    for (int j=0;j<4;j++){
      f32x4 v = acc[i][j];
      int n = cw + 16*j + lane15;
      #pragma unroll
      for (int r=0;r<4;r++){
        float xv = fmaxf(v[r] + bj[j], 0.f);
        int m = r0 + rw + 16*i + 4*lgrp + r;
        if (STATS){
          Cf[(size_t)m*HD + n] = xv;
          sj[j] += xv;
          qj[j] = fmaf(xv, xv, qj[j]);
        } else {
          unsigned short h = bf16rne(xv);
          Ch[(size_t)m*HD + n] = h;
          Cl[(size_t)m*HD + n] = bf16rne(xv - bf16tof(h));
        }
      }
    }
  }
  if (STATS){
    #pragma unroll
    for (int j=0;j<4;j++){
      float s = sj[j], q = qj[j];
      s += __shfl_xor(s, 16); s += __shfl_xor(s, 32);
      q += __shfl_xor(q, 16); q += __shfl_xor(q, 32);
      if (lgrp == 0){
        SS[(w>>1)*128 + cw + 16*j + lane15] = s;
        SQ[(w>>1)*128 + cw + 16*j + lane15] = q;
      }
    }
    __syncthreads();
    if (tid < HD){
      float s = SS[tid] + SS[128 + tid];
      float q = SQ[tid] + SQ[128 + tid];
      atomicAdd(&bnsum[tid], s);
      atomicAdd(&bnsq[tid], q);
      atomicAdd(&gsumL[(blockIdx.x >> 3)*HD + tid], s);   // per-batch raw colsum
    }
  }
}

// ---------------- fused: BN (from atomic sums) + mean-aggregate -> bf16 hi/lo z ----------------
__global__ __launch_bounds__(128) void k_agg_bn(const float* __restrict__ raw, const int* __restrict__ rowp,
                                                const int* __restrict__ csr, const float* __restrict__ invdeg,
                                                const float* __restrict__ bnsum_l, const float* __restrict__ bnsq_l,
                                                const float* __restrict__ gamma_l, const float* __restrict__ beta_l,
                                                unsigned short* __restrict__ zh, unsigned short* __restrict__ zl){
  int i = blockIdx.x;
  int f = threadIdx.x;
  int a = rowp[i], bnd = rowp[i+1];
  float s = 0.f;
  for (int k = a; k < bnd; k++) s += raw[(size_t)csr[k]*HD + f];
  float mu  = bnsum_l[f] * (1.0f/NND);
  float var = bnsq_l[f] * (1.0f/NND) - mu*mu;
  float sc  = gamma_l[f] * rsqrtf(var + 1e-5f);
  float sh  = beta_l[f] - mu*sc;
  size_t idx = (size_t)i*HD + f;
  float vi = fmaf(raw[idx], sc, sh);
  float zz = vi + fmaf(invdeg[i]*sc, s, (bnd > a) ? sh : 0.f);
  unsigned short h = bf16rne(zz);
  zh[idx] = h;
  zl[idx] = bf16rne(zz - bf16tof(h));
}

// ---------------- build aug rows (npool + gpool on the fly) ----------------
__global__ __launch_bounds__(256) void k_build_aug(const int* __restrict__ mrows, const int* __restrict__ mcols,
                                                   const float* __restrict__ raw0, const float* __restrict__ raw1,
                                                   const float* __restrict__ raw2, const float* __restrict__ raw3,
                                                   const float* __restrict__ bnsum, const float* __restrict__ bnsq,
                                                   const float* __restrict__ bng, const float* __restrict__ bnb,
                                                   const float* __restrict__ gsumL, float* __restrict__ aug){
  int idx = blockIdx.x;     // 0..4095: first 2048 = row nodes, next 2048 = col nodes
  int t = threadIdx.x;
  int j = idx & 2047;
  int rg = mrows[j];
  int b = rg >> 10;
  int g = (idx >= 2048) ? ((b << 10) | mcols[j]) : rg;
  int f = (t < 128) ? t : (t - 128);
  float sc[4], sh[4];
  #pragma unroll
  for (int l=0;l<4;l++){
    float mu  = bnsum[l*128+f] * (1.0f/NND);
    float var = bnsq[l*128+f] * (1.0f/NND) - mu*mu;
    sc[l] = bng[l*128+f] * rsqrtf(var + 1e-5f);
    sh[l] = bnb[l*128+f] - mu*sc[l];
  }
  float v;
  if (t < 128){
    size_t o = (size_t)g*HD + f;
    v = fmaf(sc[0], raw0[o], sh[0]);
    v = fmaf(sc[1], raw1[o], v + sh[1]);
    v = fmaf(sc[2], raw2[o], v + sh[2]);
    v = fmaf(sc[3], raw3[o], v + sh[3]);
  } else {
    float gacc = 0.f;
    #pragma unroll
    for (int l=0;l<4;l++)
      gacc += fmaf(sc[l], gsumL[(l*32 + b)*HD + f], 1024.0f*sh[l]);
    v = gacc * (1.0f/1024.0f);
  }
  aug[(size_t)idx*256 + t] = v;
}

// fused policy layer: C = tanh(A@W1+b1)@W2+b2.  64-row tile (proven).
template<int K1>
__global__ __launch_bounds__(256) void k_pol(const float* __restrict__ A, const float* __restrict__ W1,
                                             const float* __restrict__ b1, const float* __restrict__ W2,
                                             const float* __restrict__ b2, float* __restrict__ C){
  __shared__ float S1[32*128 + 64*36];
  __shared__ float T[64*132];
  int tid = threadIdx.x;
  int r0 = blockIdx.x * 64;
  int tc = tid & 15, rg = tid >> 4;
  int c0 = tc * 4;
  float4 acc0[4], acc1[4];
  #pragma unroll
  for (int j=0;j<4;j++){ acc0[j] = make_float4(0,0,0,0); acc1[j] = make_float4(0,0,0,0); }
  for (int k0 = 0; k0 < K1; k0 += 32){
    __syncthreads();
    #pragma unroll
    for (int u=0;u<4;u++){
      int e = tid + u*256;
      *(float4*)&S1[(e>>5)*HD + ((e&31)<<2)] = *(const float4*)&W1[(size_t)(k0 + (e>>5))*HD + ((e&31)<<2)];
    }
    #pragma unroll
    for (int u=0;u<2;u++){
      int e = tid + u*256;
      *(float4*)&S1[4096 + (e>>3)*36 + ((e&7)<<2)] = *(const float4*)&A[(size_t)(r0 + (e>>3))*K1 + k0 + ((e&7)<<2)];
    }
    __syncthreads();
    #pragma unroll
    for (int kk=0; kk<32; kk+=4){
      float4 w0[4], w1[4];
      #pragma unroll
      for (int q=0;q<4;q++){
        w0[q] = *(const float4*)&S1[(kk+q)*HD + c0];
        w1[q] = *(const float4*)&S1[(kk+q)*HD + c0 + 64];
      }
      #pragma unroll
      for (int j=0;j<4;j++){
        float4 av = *(const float4*)&S1[4096 + (rg+16*j)*36 + kk];
        fma4(acc0[j], av.x, w0[0]); fma4(acc1[j], av.x, w1[0]);
        fma4(acc0[j], av.y, w0[1]); fma4(acc1[j], av.y, w1[1]);
        fma4(acc0[j], av.z, w0[2]); fma4(acc1[j], av.z, w1[2]);
        fma4(acc0[j], av.w, w0[3]); fma4(acc1[j], av.w, w1[3]);
      }
    }
  }
  {
    float4 bA = *(const float4*)&b1[c0];
    float4 bB = *(const float4*)&b1[c0+64];
    #pragma unroll
    for (int j=0;j<4;j++){
      int r = rg + 16*j;
      float4 v0 = acc0[j], v1 = acc1[j];
      v0.x = tanhf(v0.x + bA.x); v0.y = tanhf(v0.y + bA.y);
      v0.z = tanhf(v0.z + bA.z); v0.w = tanhf(v0.w + bA.w);
      v1.x = tanhf(v1.x + bB.x); v1.y = tanhf(v1.y + bB.y);
      v1.z = tanhf(v1.z + bB.z); v1.w = tanhf(v1.w + bB.w);
      *(float4*)&T[r*132 + c0] = v0;
      *(float4*)&T[r*132 + c0 + 64] = v1;
    }
  }
  float4 d0[4], d1[4];
  #pragma unroll
  for (int j=0;j<4;j++){ d0[j] = make_float4(0,0,0,0); d1[j] = make_float4(0,0,0,0); }
  for (int k0 = 0; k0 < HD; k0 += 32){
    __syncthreads();
    #pragma unroll
    for (int u=0;u<4;u++){
      int e = tid + u*256;
      *(float4*)&S1[(e>>5)*HD + ((e&31)<<2)] = *(const float4*)&W2[(size_t)(k0 + (e>>5))*HD + ((e&31)<<2)];
    }
    __syncthreads();
    #pragma unroll
    for (int kk=0; kk<32; kk+=4){
      float4 w0[4], w1[4];
      #pragma unroll
      for (int q=0;q<4;q++){
        w0[q] = *(const float4*)&S1[(kk+q)*HD + c0];
        w1[q] = *(const float4*)&S1[(kk+q)*HD + c0 + 64];
      }
      #pragma unroll
      for (int j=0;j<4;j++){
        float4 av = *(const float4*)&T[(rg+16*j)*132 + k0 + kk];
        fma4(d0[j], av.x, w0[0]); fma4(d1[j], av.x, w1[0]);
        fma4(d0[j], av.y, w0[1]); fma4(d1[j], av.y, w1[1]);
        fma4(d0[j], av.z, w0[2]); fma4(d1[j], av.z, w1[2]);
        fma4(d0[j], av.w, w0[3]); fma4(d1[j], av.w, w1[3]);
      }
    }
  }
  float4 bA = *(const float4*)&b2[c0];
  float4 bB = *(const float4*)&b2[c0+64];
  #pragma unroll
  for (int j=0;j<4;j++){
    int row = r0 + rg + 16*j;
    float4 v0 = d0[j], v1 = d1[j];
    v0.x += bA.x; v0.y += bA.y; v0.z += bA.z; v0.w += bA.w;
    v1.x += bB.x; v1.y += bB.y; v1.z += bB.z; v1.w += bB.w;
    *(float4*)&C[(size_t)row*HD + c0] = v0;
    *(float4*)&C[(size_t)row*HD + c0 + 64] = v1;
  }
}

// score + per-batch sparse softmax (dedup of repeated cells) + scatter
__global__ __launch_bounds__(64) void k_score(const float* __restrict__ Z, const int* __restrict__ mrows,
                                              const int* __restrict__ mcols, float* __restrict__ out){
  __shared__ int rr[64]; __shared__ int cc[64]; __shared__ float red[64];
  int b = blockIdx.x, f = threadIdx.x;
  int i = b*64 + f;
  int rg = mrows[i];
  int row = rg & 1023;
  int col = mcols[i];
  const float4* zr = (const float4*)&Z[(size_t)i*HD];
  const float4* zc = (const float4*)&Z[(size_t)(NPAIR + i)*HD];
  float s = 0.f;
  #pragma unroll
  for (int k=0;k<32;k++){
    float4 a = zr[k], c = zc[k];
    s = fmaf(a.x,c.x, fmaf(a.y,c.y, fmaf(a.z,c.z, fmaf(a.w,c.w, s))));
  }
  rr[f]=row; cc[f]=col; red[f]=s;
  __syncthreads();
  for (int d=32; d>0; d>>=1){
    if (f<d) red[f] = fmaxf(red[f], red[f+d]);
    __syncthreads();
  }
  float m = red[0];
  __syncthreads();
  bool first = true;
  for (int j=0;j<f;j++) if (rr[j]==row && cc[j]==col) first = false;
  float e = expf(s - m);
  red[f] = first ? e : 0.0f;
  __syncthreads();
  for (int d=32; d>0; d>>=1){
    if (f<d) red[f] += red[f+d];
    __syncthreads();
  }
  float denom = red[0];
  out[(size_t)b*1048576 + row*1024 + col] = e / denom;
}

extern "C" void kernel_launch(void* const* d_in, const int* in_sizes, int n_in,
                              void* d_out, int out_size, void* d_ws, size_t ws_size,
                              hipStream_t stream){
  const float* x     = (const float*)d_in[0];
  const int*   ei    = (const int*)d_in[1];
  const int*   mrows = (const int*)d_in[3];
  const int*   mcols = (const int*)d_in[4];
  const float* g0w1  = (const float*)d_in[5];
  const float* g0b1  = (const float*)d_in[6];
  const float* g0w2  = (const float*)d_in[7];
  const float* g0b2  = (const float*)d_in[8];
  const float* gw1   = (const float*)d_in[9];
  const float* gb1   = (const float*)d_in[10];
  const float* gw2   = (const float*)d_in[11];
  const float* gb2   = (const float*)d_in[12];
  const float* bng   = (const float*)d_in[13];
  const float* bnb   = (const float*)d_in[14];
  const float* p0w1  = (const float*)d_in[15];
  const float* p0b1  = (const float*)d_in[16];
  const float* p0w2  = (const float*)d_in[17];
  const float* p0b2  = (const float*)d_in[18];
  const float* pw1   = (const float*)d_in[19];
  const float* pb1   = (const float*)d_in[20];
  const float* pw2   = (const float*)d_in[21];
  const float* pb2   = (const float*)d_in[22];

  float* fw    = (float*)d_ws;
  float* raw0  = fw;                        // N*H fp32
  float* raw1  = fw + 4194304;
  float* raw2  = fw + 8388608;
  float* raw3  = fw + 12582912;
  float* aug   = fw + 16777216;             // 4096*256
  float* pX    = fw + 17825792;             // 4096*128
  float* pY    = fw + 18350080;
  float* pZ    = fw + 18874368;
  float* invdeg= fw + 19398656;             // N
  // meta region (zeroed by k_init each call): cnt, fillc, bnsum, bnsq, gsumL
  float* meta  = fw + 19431424;
  int*   cnt   = (int*)meta;                // N
  int*   fillc = cnt + NND;                 // N
  float* bnsum = (float*)(fillc + NND);     // 4*128
  float* bnsq  = bnsum + 512;               // 4*128
  float* gsumL = bnsq + 512;                // 4*32*128
  const int META4 = (NND + NND + 512 + 512 + 16384) / 4;   // float4 count = 20736
  int*   rowp  = (int*)(gsumL + 16384);     // N+1
  int*   csr   = rowp + NND + 1;            // E
  unsigned short* us = (unsigned short*)(fw + 20500000);
  unsigned short* zHi  = us;                // N*H bf16
  unsigned short* zLo  = us + 4194304;
  unsigned short* tHi  = us + 8388608;
  unsigned short* tLo  = us + 12582912;
  unsigned short* WThi = us + 16777216;     // 7*128*128
  unsigned short* WTlo = us + 16891904;
  float* raws[4] = {raw0, raw1, raw2, raw3};

  const int* src = ei;
  const int* dst = ei + NE;

  hipLaunchKernelGGL(k_init, dim3(2112), dim3(256), 0, stream, (float4*)d_out, out_size/4,
                     (float4*)meta, META4, g0w2, gw1, gw2, WThi, WTlo);

  hipLaunchKernelGGL(k_count, dim3(NE/256), dim3(256), 0, stream, dst, cnt);
  hipLaunchKernelGGL(k_scan, dim3(1), dim3(1024), 0, stream, cnt, rowp, invdeg);
  hipLaunchKernelGGL(k_fill, dim3(NE/256), dim3(256), 0, stream, src, dst, rowp, fillc, csr);

  // layer 0 (fused agg + first matmul)
  hipLaunchKernelGGL(k_l0, dim3(NND/2), dim3(256), 0, stream, x, rowp, csr, invdeg, g0w1, g0b1, tHi, tLo);
  hipLaunchKernelGGL((k_mgemm<1>), dim3(NBLK), dim3(256), 0, stream, tHi, tLo, WThi, WTlo, g0b2,
                     raw0, (unsigned short*)nullptr, (unsigned short*)nullptr,
                     bnsum, bnsq, gsumL);

  // layers 1..3
  for (int l=0;l<3;l++){
    hipLaunchKernelGGL(k_agg_bn, dim3(NND), dim3(128), 0, stream, raws[l], rowp, csr, invdeg,
                       bnsum + l*128, bnsq + l*128, bng + l*128, bnb + l*128, zHi, zLo);
    hipLaunchKernelGGL((k_mgemm<0>), dim3(NBLK), dim3(256), 0, stream, zHi, zLo,
                       WThi + (1+l)*16384, WTlo + (1+l)*16384, gb1 + l*128,
                       (float*)nullptr, tHi, tLo, (float*)nullptr, (float*)nullptr, (float*)nullptr);
    hipLaunchKernelGGL((k_mgemm<1>), dim3(NBLK), dim3(256), 0, stream, tHi, tLo,
                       WThi + (4+l)*16384, WTlo + (4+l)*16384, gb2 + l*128,
                       raws[l+1], (unsigned short*)nullptr, (unsigned short*)nullptr,
                       bnsum + (l+1)*128, bnsq + (l+1)*128, gsumL + (l+1)*4096);
  }

  // policy on the 4096 referenced node instances only
  hipLaunchKernelGGL(k_build_aug, dim3(4096), dim3(256), 0, stream, mrows, mcols,
                     raw0, raw1, raw2, raw3, bnsum, bnsq, bng, bnb, gsumL, aug);
  hipLaunchKernelGGL((k_pol<256>), dim3(64), dim3(256), 0, stream, aug, p0w1, p0b1, p0w2, p0b2, pX);
  hipLaunchKernelGGL((k_pol<128>), dim3(64), dim3(256), 0, stream, pX, pw1, pb1, pw2, pb2, pY);
  hipLaunchKernelGGL((k_pol<128>), dim3(64), dim3(256), 0, stream, pY, pw1 + 16384, pb1 + 128, pw2 + 16384, pb2 + 128, pZ);

  hipLaunchKernelGGL(k_score, dim3(32), dim3(64), 0, stream, pZ, mrows, mcols, (float*)d_out);
}

// Round 11
// 393.795 us; speedup vs baseline: 1.0949x; 1.0949x over previous
//
#include <hip/hip_runtime.h>

#define NND 32768      // total nodes N = B*NNODES
#define NE  262144     // edges
#define HD 128
#define NPAIR 2048     // B*FEAS
#define NBLK 256       // layer-0 mgemm blocks (NND/128)
#define SQOFF 32768    // NBLK*128 (layer-0 part slot sq offset)
#define GBLK 512       // glayer blocks (NND/64)

typedef __attribute__((ext_vector_type(8))) short short8;
typedef __attribute__((ext_vector_type(4))) float f32x4;

__device__ __forceinline__ void fma4(float4& a, float s, const float4& w){
  a.x = fmaf(s, w.x, a.x);
  a.y = fmaf(s, w.y, a.y);
  a.z = fmaf(s, w.z, a.z);
  a.w = fmaf(s, w.w, a.w);
}

__device__ __forceinline__ unsigned short bf16rne(float x){
  unsigned int u = __float_as_uint(x);
  unsigned int r = u + 0x7FFFu + ((u >> 16) & 1u);
  return (unsigned short)(r >> 16);
}
__device__ __forceinline__ float bf16tof(unsigned short h){
  return __uint_as_float(((unsigned int)h) << 16);
}

// ---------------- output zero-fill ----------------
__global__ __launch_bounds__(256) void k_zero(float4* __restrict__ p, int n4){
  int i = blockIdx.x*256 + threadIdx.x;
  int stride = gridDim.x*256;
  float4 z = make_float4(0.f,0.f,0.f,0.f);
  for (; i < n4; i += stride) p[i] = z;
}

// ---------------- weight split+transpose: W[k][n] fp32 -> WT{hi,lo}[n][k] bf16 ----------------
__global__ __launch_bounds__(256) void k_wsplit(const float* __restrict__ g0w2, const float* __restrict__ gw1,
                                                const float* __restrict__ gw2, unsigned short* __restrict__ WThi,
                                                unsigned short* __restrict__ WTlo){
  __shared__ float tile[16*129];
  int kblk = blockIdx.x, mat = blockIdx.y;
  int k0 = kblk * 16;
  const float* W = (mat == 0) ? g0w2 : ((mat < 4) ? (gw1 + (mat-1)*16384) : (gw2 + (mat-4)*16384));
  int t = threadIdx.x;
  {
    int kk = t >> 4, n0 = (t & 15) * 8;
    float4 v0 = *(const float4*)&W[(size_t)(k0+kk)*HD + n0];
    float4 v1 = *(const float4*)&W[(size_t)(k0+kk)*HD + n0 + 4];
    tile[kk*129 + n0+0] = v0.x; tile[kk*129 + n0+1] = v0.y;
    tile[kk*129 + n0+2] = v0.z; tile[kk*129 + n0+3] = v0.w;
    tile[kk*129 + n0+4] = v1.x; tile[kk*129 + n0+5] = v1.y;
    tile[kk*129 + n0+6] = v1.z; tile[kk*129 + n0+7] = v1.w;
  }
  __syncthreads();
  int n = t >> 1, koff = (t & 1) * 8;
  short8 hv, lv;
  #pragma unroll
  for (int q=0;q<8;q++){
    float v = tile[(koff+q)*129 + n];
    unsigned short h = bf16rne(v);
    hv[q] = (short)h;
    lv[q] = (short)bf16rne(v - bf16tof(h));
  }
  size_t o = (size_t)mat*16384 + (size_t)n*HD + k0 + koff;
  *(short8*)&WThi[o] = hv;
  *(short8*)&WTlo[o] = lv;
}

// ---------------- CSR build ----------------
__global__ __launch_bounds__(256) void k_count(const int* __restrict__ dst, int* __restrict__ cnt){
  int e = blockIdx.x*256 + threadIdx.x;
  if (e < NE) atomicAdd(&cnt[dst[e]], 1);
}

__global__ __launch_bounds__(1024) void k_scan(const int* __restrict__ cnt, int* __restrict__ rowp,
                                               float* __restrict__ invdeg){
  __shared__ int part[1024];
  int t = threadIdx.x;
  int base = t*32;
  int local[32];
  int s = 0;
  #pragma unroll
  for (int j=0;j<32;j++){ local[j] = s; s += cnt[base+j]; }
  part[t] = s;
  __syncthreads();
  for (int d=1; d<1024; d<<=1){
    int v = (t>=d) ? part[t-d] : 0;
    __syncthreads();
    part[t] += v;
    __syncthreads();
  }
  int off = (t==0) ? 0 : part[t-1];
  #pragma unroll
  for (int j=0;j<32;j++){
    rowp[base+j] = off + local[j];
    int c = cnt[base+j];
    invdeg[base+j] = 1.0f / (float)(c > 0 ? c : 1);
  }
  if (t == 1023) rowp[NND] = off + s;
}

__global__ __launch_bounds__(256) void k_fill(const int* __restrict__ src, const int* __restrict__ dst,
                                              const int* __restrict__ rowp, int* __restrict__ fillc,
                                              int* __restrict__ csr){
  int e = blockIdx.x*256 + threadIdx.x;
  if (e < NE){
    int d = dst[e];
    int p = atomicAdd(&fillc[d], 1);
    csr[rowp[d] + p] = src[e];
  }
}

// ---------------- layer-0 aggregation (IN=8) ----------------
__global__ __launch_bounds__(256) void k_agg8(const float* __restrict__ x, const int* __restrict__ rowp,
                                              const int* __restrict__ csr, const float* __restrict__ invdeg,
                                              float* __restrict__ z8){
  int i = blockIdx.x*256 + threadIdx.x;
  float s[8] = {0,0,0,0,0,0,0,0};
  int a = rowp[i], bnd = rowp[i+1];
  for (int k=a;k<bnd;k++){
    int j = csr[k];
    const float4* p = (const float4*)&x[(size_t)j*8];
    float4 u0 = p[0], u1 = p[1];
    s[0]+=u0.x; s[1]+=u0.y; s[2]+=u0.z; s[3]+=u0.w;
    s[4]+=u1.x; s[5]+=u1.y; s[6]+=u1.z; s[7]+=u1.w;
  }
  float iv = invdeg[i];
  const float4* xp = (const float4*)&x[(size_t)i*8];
  float4 x0 = xp[0], x1 = xp[1];
  float4 o0, o1;
  o0.x = x0.x + s[0]*iv; o0.y = x0.y + s[1]*iv; o0.z = x0.z + s[2]*iv; o0.w = x0.w + s[3]*iv;
  o1.x = x1.x + s[4]*iv; o1.y = x1.y + s[5]*iv; o1.z = x1.z + s[6]*iv; o1.w = x1.w + s[7]*iv;
  ((float4*)&z8[(size_t)i*8])[0] = o0;
  ((float4*)&z8[(size_t)i*8])[1] = o1;
}

// [N x 8] @ [8 x 128] + bias, ReLU -> bf16 hi/lo pair
__global__ __launch_bounds__(256) void k_gemm8(const float* __restrict__ A, const float* __restrict__ W,
                                               const float* __restrict__ bias, unsigned short* __restrict__ Ch,
                                               unsigned short* __restrict__ Cl){
  __shared__ float Ws[8*HD];
  __shared__ float bs[HD];
  int tid = threadIdx.x;
  for (int u=tid; u<8*HD; u+=256) Ws[u] = W[u];
  if (tid < HD) bs[tid] = bias[tid];
  __syncthreads();
  int g = blockIdx.x*256 + tid;     // over NND*HD
  int row = g >> 7, c = g & 127;
  const float4* a4 = (const float4*)&A[(size_t)row*8];
  float4 a0 = a4[0], a1 = a4[1];
  float s = bs[c];
  s = fmaf(a0.x, Ws[0*128+c], s); s = fmaf(a0.y, Ws[1*128+c], s);
  s = fmaf(a0.z, Ws[2*128+c], s); s = fmaf(a0.w, Ws[3*128+c], s);
  s = fmaf(a1.x, Ws[4*128+c], s); s = fmaf(a1.y, Ws[5*128+c], s);
  s = fmaf(a1.z, Ws[6*128+c], s); s = fmaf(a1.w, Ws[7*128+c], s);
  s = fmaxf(s, 0.0f);
  unsigned short h = bf16rne(s);
  Ch[g] = h;
  Cl[g] = bf16rne(s - bf16tof(h));
}

// ---------------- layer-0 MFMA GEMM (128-row, bf16x3, fp32 out + part stats) — R9-proven ----------------
__global__ __launch_bounds__(256) void k_mgemm1(const unsigned short* __restrict__ Ah, const unsigned short* __restrict__ Al,
                                                const unsigned short* __restrict__ Wh, const unsigned short* __restrict__ Wl,
                                                const float* __restrict__ bias, float* __restrict__ Cf,
                                                float* __restrict__ part){
  __shared__ unsigned short AH[128*40], AL[128*40], WH[128*40], WL[128*40];
  __shared__ float SS[256], SQ[256];
  int tid = threadIdx.x;
  int r0 = blockIdx.x * 128;
  int row = tid >> 1, half = tid & 1;
  int l = tid & 63, w = tid >> 6;
  int lane15 = l & 15, lgrp = l >> 4;
  int rw = (w >> 1) * 64, cw = (w & 1) * 64;

  f32x4 acc[4][4];
  #pragma unroll
  for (int i=0;i<4;i++)
    #pragma unroll
    for (int j=0;j<4;j++){ f32x4 z = {0.f,0.f,0.f,0.f}; acc[i][j] = z; }

  size_t abase = (size_t)(r0 + row)*HD + half*16;
  size_t wbase = (size_t)row*HD + half*16;
  float4 p0 = *(const float4*)&Ah[abase];     float4 p1 = *(const float4*)&Ah[abase+8];
  float4 p2 = *(const float4*)&Al[abase];     float4 p3 = *(const float4*)&Al[abase+8];
  float4 p4 = *(const float4*)&Wh[wbase];     float4 p5 = *(const float4*)&Wh[wbase+8];
  float4 p6 = *(const float4*)&Wl[wbase];     float4 p7 = *(const float4*)&Wl[wbase+8];

  for (int k0 = 0; k0 < 128; k0 += 32){
    __syncthreads();
    int ldst = row*40 + half*16;
    *(float4*)&AH[ldst] = p0; *(float4*)&AH[ldst+8] = p1;
    *(float4*)&AL[ldst] = p2; *(float4*)&AL[ldst+8] = p3;
    *(float4*)&WH[ldst] = p4; *(float4*)&WH[ldst+8] = p5;
    *(float4*)&WL[ldst] = p6; *(float4*)&WL[ldst+8] = p7;
    __syncthreads();
    if (k0 < 96){
      p0 = *(const float4*)&Ah[abase + k0+32]; p1 = *(const float4*)&Ah[abase + k0+40];
      p2 = *(const float4*)&Al[abase + k0+32]; p3 = *(const float4*)&Al[abase + k0+40];
      p4 = *(const float4*)&Wh[wbase + k0+32]; p5 = *(const float4*)&Wh[wbase + k0+40];
      p6 = *(const float4*)&Wl[wbase + k0+32]; p7 = *(const float4*)&Wl[wbase + k0+40];
    }
    short8 ah[4], al[4], wh[4], wl[4];
    #pragma unroll
    for (int i=0;i<4;i++){
      int ar = (rw + 16*i + lane15)*40 + lgrp*8;
      ah[i] = *(const short8*)&AH[ar];
      al[i] = *(const short8*)&AL[ar];
      int wr = (cw + 16*i + lane15)*40 + lgrp*8;
      wh[i] = *(const short8*)&WH[wr];
      wl[i] = *(const short8*)&WL[wr];
    }
    #pragma unroll
    for (int i=0;i<4;i++){
      #pragma unroll
      for (int j=0;j<4;j++){
        acc[i][j] = __builtin_amdgcn_mfma_f32_16x16x32_bf16(ah[i], wh[j], acc[i][j], 0, 0, 0);
        acc[i][j] = __builtin_amdgcn_mfma_f32_16x16x32_bf16(al[i], wh[j], acc[i][j], 0, 0, 0);
        acc[i][j] = __builtin_amdgcn_mfma_f32_16x16x32_bf16(ah[i], wl[j], acc[i][j], 0, 0, 0);
      }
    }
  }

  float bj[4], sj[4] = {0,0,0,0}, qj[4] = {0,0,0,0};
  #pragma unroll
  for (int j=0;j<4;j++) bj[j] = bias[cw + 16*j + lane15];
  #pragma unroll
  for (int i=0;i<4;i++){
    #pragma unroll
    for (int j=0;j<4;j++){
      f32x4 v = acc[i][j];
      int n = cw + 16*j + lane15;
      #pragma unroll
      for (int r=0;r<4;r++){
        float xv = fmaxf(v[r] + bj[j], 0.f);
        int m = r0 + rw + 16*i + 4*lgrp + r;
        Cf[(size_t)m*HD + n] = xv;
        sj[j] += xv;
        qj[j] = fmaf(xv, xv, qj[j]);
      }
    }
  }
  #pragma unroll
  for (int j=0;j<4;j++){
    float s = sj[j], q = qj[j];
    s += __shfl_xor(s, 16); s += __shfl_xor(s, 32);
    q += __shfl_xor(q, 16); q += __shfl_xor(q, 32);
    if (lgrp == 0){
      SS[(w>>1)*128 + cw + 16*j + lane15] = s;
      SQ[(w>>1)*128 + cw + 16*j + lane15] = q;
    }
  }
  __syncthreads();
  if (tid < HD){
    part[blockIdx.x*HD + tid] = SS[tid] + SS[128 + tid];
    part[SQOFF + blockIdx.x*HD + tid] = SQ[tid] + SQ[128 + tid];
  }
}

// ---------------- fused GIN layer: raw = relu( relu(z@W1+b1) @ W2 + b2 ) + part stats ----------------
// 64-row tile, 4 waves (wave w: cols w*32..w*32+31, all 64 rows). t in LDS bf16 hi/lo (stride 136).
__global__ __launch_bounds__(256) void k_glayer(const unsigned short* __restrict__ Ah, const unsigned short* __restrict__ Al,
                                                const unsigned short* __restrict__ W1h, const unsigned short* __restrict__ W1l,
                                                const float* __restrict__ b1,
                                                const unsigned short* __restrict__ W2h, const unsigned short* __restrict__ W2l,
                                                const float* __restrict__ b2,
                                                float* __restrict__ Cf, float* __restrict__ part){
  __shared__ unsigned short AH[64*40], AL[64*40], WH[128*40], WL[128*40];
  __shared__ unsigned short TH[64*136], TL[64*136];
  __shared__ float SS[128], SQ[128];
  int tid = threadIdx.x;
  int r0 = blockIdx.x * 64;
  int l = tid & 63, w = tid >> 6;
  int lane15 = l & 15, lgrp = l >> 4;
  int cw = w * 32;

  f32x4 acc[4][2];
  #pragma unroll
  for (int i=0;i<4;i++){
    #pragma unroll
    for (int j=0;j<2;j++){ f32x4 z = {0.f,0.f,0.f,0.f}; acc[i][j] = z; }
  }

  int arow = tid >> 2, akoff = (tid & 3) * 8;
  size_t abase = (size_t)(r0 + arow)*HD + akoff;
  int wrow = tid >> 1, whalf = (tid & 1) * 16;
  size_t wbase = (size_t)wrow*HD + whalf;
  float4 pa0 = *(const float4*)&Ah[abase];
  float4 pa1 = *(const float4*)&Al[abase];
  float4 pw0 = *(const float4*)&W1h[wbase], pw1 = *(const float4*)&W1h[wbase+8];
  float4 pw2 = *(const float4*)&W1l[wbase], pw3 = *(const float4*)&W1l[wbase+8];

  // ---- phase 1: t = relu(z @ W1 + b1) ----
  for (int k0 = 0; k0 < 128; k0 += 32){
    __syncthreads();
    *(float4*)&AH[arow*40 + akoff] = pa0;
    *(float4*)&AL[arow*40 + akoff] = pa1;
    int wd = wrow*40 + whalf;
    *(float4*)&WH[wd] = pw0; *(float4*)&WH[wd+8] = pw1;
    *(float4*)&WL[wd] = pw2; *(float4*)&WL[wd+8] = pw3;
    __syncthreads();
    if (k0 < 96){
      pa0 = *(const float4*)&Ah[abase + k0+32];
      pa1 = *(const float4*)&Al[abase + k0+32];
      pw0 = *(const float4*)&W1h[wbase + k0+32]; pw1 = *(const float4*)&W1h[wbase + k0+40];
      pw2 = *(const float4*)&W1l[wbase + k0+32]; pw3 = *(const float4*)&W1l[wbase + k0+40];
    }
    short8 ah[4], al4[4], wh[2], wl[2];
    #pragma unroll
    for (int i=0;i<4;i++){
      int ar = (16*i + lane15)*40 + lgrp*8;
      ah[i]  = *(const short8*)&AH[ar];
      al4[i] = *(const short8*)&AL[ar];
    }
    #pragma unroll
    for (int j=0;j<2;j++){
      int wr = (cw + 16*j + lane15)*40 + lgrp*8;
      wh[j] = *(const short8*)&WH[wr];
      wl[j] = *(const short8*)&WL[wr];
    }
    #pragma unroll
    for (int i=0;i<4;i++){
      #pragma unroll
      for (int j=0;j<2;j++){
        acc[i][j] = __builtin_amdgcn_mfma_f32_16x16x32_bf16(ah[i],  wh[j], acc[i][j], 0, 0, 0);
        acc[i][j] = __builtin_amdgcn_mfma_f32_16x16x32_bf16(al4[i], wh[j], acc[i][j], 0, 0, 0);
        acc[i][j] = __builtin_amdgcn_mfma_f32_16x16x32_bf16(ah[i],  wl[j], acc[i][j], 0, 0, 0);
      }
    }
  }
  // epilogue 1: bias+relu, split to bf16 hi/lo into TH/TL (fresh buffers, no alias with phase-1 arrays)
  {
    float bA = b1[cw + lane15], bB = b1[cw + 16 + lane15];
    #pragma unroll
    for (int i=0;i<4;i++){
      #pragma unroll
      for (int j=0;j<2;j++){
        f32x4 v = acc[i][j];
        float bb = j ? bB : bA;
        int n = cw + 16*j + lane15;
        #pragma unroll
        for (int r=0;r<4;r++){
          float xv = fmaxf(v[r] + bb, 0.f);
          int m = 16*i + 4*lgrp + r;
          unsigned short h = bf16rne(xv);
          TH[m*136 + n] = h;
          TL[m*136 + n] = bf16rne(xv - bf16tof(h));
        }
      }
    }
  }
  // ---- phase 2: raw = relu(t @ W2 + b2) ----
  #pragma unroll
  for (int i=0;i<4;i++){
    #pragma unroll
    for (int j=0;j<2;j++){ f32x4 z = {0.f,0.f,0.f,0.f}; acc[i][j] = z; }
  }
  pw0 = *(const float4*)&W2h[wbase]; pw1 = *(const float4*)&W2h[wbase+8];
  pw2 = *(const float4*)&W2l[wbase]; pw3 = *(const float4*)&W2l[wbase+8];
  for (int k0 = 0; k0 < 128; k0 += 32){
    __syncthreads();   // covers TH/TL writes (first iter) + WH reads from previous chunk
    int wd = wrow*40 + whalf;
    *(float4*)&WH[wd] = pw0; *(float4*)&WH[wd+8] = pw1;
    *(float4*)&WL[wd] = pw2; *(float4*)&WL[wd+8] = pw3;
    __syncthreads();
    if (k0 < 96){
      pw0 = *(const float4*)&W2h[wbase + k0+32]; pw1 = *(const float4*)&W2h[wbase + k0+40];
      pw2 = *(const float4*)&W2l[wbase + k0+32]; pw3 = *(const float4*)&W2l[wbase + k0+40];
    }
    short8 ah[4], al4[4], wh[2], wl[2];
    #pragma unroll
    for (int i=0;i<4;i++){
      int ar = (16*i + lane15)*136 + k0 + lgrp*8;
      ah[i]  = *(const short8*)&TH[ar];
      al4[i] = *(const short8*)&TL[ar];
    }
    #pragma unroll
    for (int j=0;j<2;j++){
      int wr = (cw + 16*j + lane15)*40 + lgrp*8;
      wh[j] = *(const short8*)&WH[wr];
      wl[j] = *(const short8*)&WL[wr];
    }
    #pragma unroll
    for (int i=0;i<4;i++){
      #pragma unroll
      for (int j=0;j<2;j++){
        acc[i][j] = __builtin_amdgcn_mfma_f32_16x16x32_bf16(ah[i],  wh[j], acc[i][j], 0, 0, 0);
        acc[i][j] = __builtin_amdgcn_mfma_f32_16x16x32_bf16(al4[i], wh[j], acc[i][j], 0, 0, 0);
        acc[i][j] = __builtin_amdgcn_mfma_f32_16x16x32_bf16(ah[i],  wl[j], acc[i][j], 0, 0, 0);
      }
    }
  }
  // epilogue 2: bias+relu, fp32 out + column stats (each wave owns its 32 cols over all 64 rows)
  {
    float bA = b2[cw + lane15], bB = b2[cw + 16 + lane15];
    float s0 = 0.f, s1 = 0.f, q0 = 0.f, q1 = 0.f;
    #pragma unroll
    for (int i=0;i<4;i++){
      #pragma unroll
      for (int j=0;j<2;j++){
        f32x4 v = acc[i][j];
        float bb = j ? bB : bA;
        int n = cw + 16*j + lane15;
        #pragma unroll
        for (int r=0;r<4;r++){
          float xv = fmaxf(v[r] + bb, 0.f);
          int m = r0 + 16*i + 4*lgrp + r;
          Cf[(size_t)m*HD + n] = xv;
          if (j){ s1 += xv; q1 = fmaf(xv, xv, q1); }
          else  { s0 += xv; q0 = fmaf(xv, xv, q0); }
        }
      }
    }
    s0 += __shfl_xor(s0, 16); s0 += __shfl_xor(s0, 32);
    s1 += __shfl_xor(s1, 16); s1 += __shfl_xor(s1, 32);
    q0 += __shfl_xor(q0, 16); q0 += __shfl_xor(q0, 32);
    q1 += __shfl_xor(q1, 16); q1 += __shfl_xor(q1, 32);
    if (lgrp == 0){
      SS[cw + lane15] = s0;      SS[cw + 16 + lane15] = s1;
      SQ[cw + lane15] = q0;      SQ[cw + 16 + lane15] = q1;
    }
  }
  __syncthreads();
  if (tid < HD){
    part[blockIdx.x*HD + tid] = SS[tid];
    part[GBLK*HD + blockIdx.x*HD + tid] = SQ[tid];
  }
}

// ---------------- BN finalize: one block per feature, generic block count ----------------
__global__ __launch_bounds__(256) void k_bn_fin(const float* __restrict__ part, int nblk,
                                                const float* __restrict__ gamma, const float* __restrict__ beta,
                                                float* __restrict__ scale, float* __restrict__ shift){
  __shared__ float rs[256];
  __shared__ float rq[256];
  int f = blockIdx.x, t = threadIdx.x;
  float s = 0.f, q = 0.f;
  for (int b = t; b < nblk; b += 256){
    s += part[b*HD + f];
    q += part[nblk*HD + b*HD + f];
  }
  rs[t] = s; rq[t] = q;
  __syncthreads();
  for (int d=128; d>0; d>>=1){
    if (t < d){ rs[t] += rs[t+d]; rq[t] += rq[t+d]; }
    __syncthreads();
  }
  if (t == 0){
    float mu  = rs[0] * (1.0f/NND);
    float var = rq[0] * (1.0f/NND) - mu*mu;
    float sc  = gamma[f] * rsqrtf(var + 1e-5f);
    scale[f] = sc;
    shift[f] = beta[f] - mu*sc;
  }
}

// ---------------- fused: BN-apply (folded) + mean-aggregate -> bf16 hi/lo z ----------------
__global__ __launch_bounds__(128) void k_agg_bn(const float* __restrict__ raw, const int* __restrict__ rowp,
                                                const int* __restrict__ csr, const float* __restrict__ invdeg,
                                                const float* __restrict__ scale, const float* __restrict__ shift,
                                                unsigned short* __restrict__ zh, unsigned short* __restrict__ zl){
  int i = blockIdx.x;
  int f = threadIdx.x;
  int a = rowp[i], bnd = rowp[i+1];
  float s = 0.f;
  for (int k = a; k < bnd; k++) s += raw[(size_t)csr[k]*HD + f];
  float sc = scale[f], sh = shift[f];
  size_t idx = (size_t)i*HD + f;
  float vi = fmaf(raw[idx], sc, sh);
  float zz = vi + fmaf(invdeg[i]*sc, s, (bnd > a) ? sh : 0.f);
  unsigned short h = bf16rne(zz);
  zh[idx] = h;
  zl[idx] = bf16rne(zz - bf16tof(h));
}

// ---------------- gpool from per-block part colsums (layer0: 8 blocks/batch; layers1-3: 16) ----------------
__global__ __launch_bounds__(128) void k_gpool(const float* __restrict__ part0, const float* __restrict__ partL,
                                               const float* __restrict__ bnsc, const float* __restrict__ bnsh,
                                               float* __restrict__ gsum){
  int b = blockIdx.x, f = threadIdx.x;
  float g;
  {
    float s = 0.f;
    #pragma unroll
    for (int t=0;t<8;t++) s += part0[(b*8 + t)*HD + f];
    g = fmaf(bnsc[f], s, 1024.0f*bnsh[f]);
  }
  #pragma unroll
  for (int l=1;l<4;l++){
    float s = 0.f;
    #pragma unroll
    for (int t=0;t<16;t++) s += partL[(l-1)*2*GBLK*HD + (b*16 + t)*HD + f];
    g += fmaf(bnsc[l*128+f], s, 1024.0f*bnsh[l*128+f]);
  }
  gsum[b*HD + f] = g;
}

// ---------------- build aug rows (npool on the fly from raw0..raw3) ----------------
__global__ __launch_bounds__(256) void k_build_aug(const int* __restrict__ mrows, const int* __restrict__ mcols,
                                                   const float* __restrict__ raw0, const float* __restrict__ raw1,
                                                   const float* __restrict__ raw2, const float* __restrict__ raw3,
                                                   const float* __restrict__ bnsc, const float* __restrict__ bnsh,
                                                   const float* __restrict__ gsum, float* __restrict__ aug){
  int idx = blockIdx.x;     // 0..4095: first 2048 = row nodes, next 2048 = col nodes
  int t = threadIdx.x;
  int j = idx & 2047;
  int rg = mrows[j];
  int b = rg >> 10;
  int g = (idx >= 2048) ? ((b << 10) | mcols[j]) : rg;
  float v;
  if (t < 128){
    size_t o = (size_t)g*HD + t;
    v = fmaf(bnsc[t],     raw0[o], bnsh[t]);
    v = fmaf(bnsc[128+t], raw1[o], v + bnsh[128+t]);
    v = fmaf(bnsc[256+t], raw2[o], v + bnsh[256+t]);
    v = fmaf(bnsc[384+t], raw3[o], v + bnsh[384+t]);
  } else {
    v = gsum[b*HD + (t-128)] * (1.0f/1024.0f);
  }
  aug[(size_t)idx*256 + t] = v;
}

// fused policy layer: C = tanh(A@W1+b1)@W2+b2.  64-row tile (proven).
template<int K1>
__global__ __launch_bounds__(256) void k_pol(const float* __restrict__ A, const float* __restrict__ W1,
                                             const float* __restrict__ b1, const float* __restrict__ W2,
                                             const float* __restrict__ b2, float* __restrict__ C){
  __shared__ float S1[32*128 + 64*36];
  __shared__ float T[64*132];
  int tid = threadIdx.x;
  int r0 = blockIdx.x * 64;
  int tc = tid & 15, rg = tid >> 4;
  int c0 = tc * 4;
  float4 acc0[4], acc1[4];
  #pragma unroll
  for (int j=0;j<4;j++){ acc0[j] = make_float4(0,0,0,0); acc1[j] = make_float4(0,0,0,0); }
  for (int k0 = 0; k0 < K1; k0 += 32){
    __syncthreads();
    #pragma unroll
    for (int u=0;u<4;u++){
      int e = tid + u*256;
      *(float4*)&S1[(e>>5)*HD + ((e&31)<<2)] = *(const float4*)&W1[(size_t)(k0 + (e>>5))*HD + ((e&31)<<2)];
    }
    #pragma unroll
    for (int u=0;u<2;u++){
      int e = tid + u*256;
      *(float4*)&S1[4096 + (e>>3)*36 + ((e&7)<<2)] = *(const float4*)&A[(size_t)(r0 + (e>>3))*K1 + k0 + ((e&7)<<2)];
    }
    __syncthreads();
    #pragma unroll
    for (int kk=0; kk<32; kk+=4){
      float4 w0[4], w1[4];
      #pragma unroll
      for (int q=0;q<4;q++){
        w0[q] = *(const float4*)&S1[(kk+q)*HD + c0];
        w1[q] = *(const float4*)&S1[(kk+q)*HD + c0 + 64];
      }
      #pragma unroll
      for (int j=0;j<4;j++){
        float4 av = *(const float4*)&S1[4096 + (rg+16*j)*36 + kk];
        fma4(acc0[j], av.x, w0[0]); fma4(acc1[j], av.x, w1[0]);
        fma4(acc0[j], av.y, w0[1]); fma4(acc1[j], av.y, w1[1]);
        fma4(acc0[j], av.z, w0[2]); fma4(acc1[j], av.z, w1[2]);
        fma4(acc0[j], av.w, w0[3]); fma4(acc1[j], av.w, w1[3]);
      }
    }
  }
  {
    float4 bA = *(const float4*)&b1[c0];
    float4 bB = *(const float4*)&b1[c0+64];
    #pragma unroll
    for (int j=0;j<4;j++){
      int r = rg + 16*j;
      float4 v0 = acc0[j], v1 = acc1[j];
      v0.x = tanhf(v0.x + bA.x); v0.y = tanhf(v0.y + bA.y);
      v0.z = tanhf(v0.z + bA.z); v0.w = tanhf(v0.w + bA.w);
      v1.x = tanhf(v1.x + bB.x); v1.y = tanhf(v1.y + bB.y);
      v1.z = tanhf(v1.z + bB.z); v1.w = tanhf(v1.w + bB.w);
      *(float4*)&T[r*132 + c0] = v0;
      *(float4*)&T[r*132 + c0 + 64] = v1;
    }
  }
  float4 d0[4], d1[4];
  #pragma unroll
  for (int j=0;j<4;j++){ d0[j] = make_float4(0,0,0,0); d1[j] = make_float4(0,0,0,0); }
  for (int k0 = 0; k0 < HD; k0 += 32){
    __syncthreads();
    #pragma unroll
    for (int u=0;u<4;u++){
      int e = tid + u*256;
      *(float4*)&S1[(e>>5)*HD + ((e&31)<<2)] = *(const float4*)&W2[(size_t)(k0 + (e>>5))*HD + ((e&31)<<2)];
    }
    __syncthreads();
    #pragma unroll
    for (int kk=0; kk<32; kk+=4){
      float4 w0[4], w1[4];
      #pragma unroll
      for (int q=0;q<4;q++){
        w0[q] = *(const float4*)&S1[(kk+q)*HD + c0];
        w1[q] = *(const float4*)&S1[(kk+q)*HD + c0 + 64];
      }
      #pragma unroll
      for (int j=0;j<4;j++){
        float4 av = *(const float4*)&T[(rg+16*j)*132 + k0 + kk];
        fma4(d0[j], av.x, w0[0]); fma4(d1[j], av.x, w1[0]);
        fma4(d0[j], av.y, w0[1]); fma4(d1[j], av.y, w1[1]);
        fma4(d0[j], av.z, w0[2]); fma4(d1[j], av.z, w1[2]);
        fma4(d0[j], av.w, w0[3]); fma4(d1[j], av.w, w1[3]);
      }
    }
  }
  float4 bA = *(const float4*)&b2[c0];
  float4 bB = *(const float4*)&b2[c0+64];
  #pragma unroll
  for (int j=0;j<4;j++){
    int row = r0 + rg + 16*j;
    float4 v0 = d0[j], v1 = d1[j];
    v0.x += bA.x; v0.y += bA.y; v0.z += bA.z; v0.w += bA.w;
    v1.x += bB.x; v1.y += bB.y; v1.z += bB.z; v1.w += bB.w;
    *(float4*)&C[(size_t)row*HD + c0] = v0;
    *(float4*)&C[(size_t)row*HD + c0 + 64] = v1;
  }
}

// score + per-batch sparse softmax (dedup of repeated cells) + scatter
__global__ __launch_bounds__(64) void k_score(const float* __restrict__ Z, const int* __restrict__ mrows,
                                              const int* __restrict__ mcols, float* __restrict__ out){
  __shared__ int rr[64]; __shared__ int cc[64]; __shared__ float red[64];
  int b = blockIdx.x, f = threadIdx.x;
  int i = b*64 + f;
  int rg = mrows[i];
  int row = rg & 1023;
  int col = mcols[i];
  const float4* zr = (const float4*)&Z[(size_t)i*HD];
  const float4* zc = (const float4*)&Z[(size_t)(NPAIR + i)*HD];
  float s = 0.f;
  #pragma unroll
  for (int k=0;k<32;k++){
    float4 a = zr[k], c = zc[k];
    s = fmaf(a.x,c.x, fmaf(a.y,c.y, fmaf(a.z,c.z, fmaf(a.w,c.w, s))));
  }
  rr[f]=row; cc[f]=col; red[f]=s;
  __syncthreads();
  for (int d=32; d>0; d>>=1){
    if (f<d) red[f] = fmaxf(red[f], red[f+d]);
    __syncthreads();
  }
  float m = red[0];
  __syncthreads();
  bool first = true;
  for (int j=0;j<f;j++) if (rr[j]==row && cc[j]==col) first = false;
  float e = expf(s - m);
  red[f] = first ? e : 0.0f;
  __syncthreads();
  for (int d=32; d>0; d>>=1){
    if (f<d) red[f] += red[f+d];
    __syncthreads();
  }
  float denom = red[0];
  out[(size_t)b*1048576 + row*1024 + col] = e / denom;
}

extern "C" void kernel_launch(void* const* d_in, const int* in_sizes, int n_in,
                              void* d_out, int out_size, void* d_ws, size_t ws_size,
                              hipStream_t stream){
  const float* x     = (const float*)d_in[0];
  const int*   ei    = (const int*)d_in[1];
  const int*   mrows = (const int*)d_in[3];
  const int*   mcols = (const int*)d_in[4];
  const float* g0w1  = (const float*)d_in[5];
  const float* g0b1  = (const float*)d_in[6];
  const float* g0w2  = (const float*)d_in[7];
  const float* g0b2  = (const float*)d_in[8];
  const float* gw1   = (const float*)d_in[9];
  const float* gb1   = (const float*)d_in[10];
  const float* gw2   = (const float*)d_in[11];
  const float* gb2   = (const float*)d_in[12];
  const float* bng   = (const float*)d_in[13];
  const float* bnb   = (const float*)d_in[14];
  const float* p0w1  = (const float*)d_in[15];
  const float* p0b1  = (const float*)d_in[16];
  const float* p0w2  = (const float*)d_in[17];
  const float* p0b2  = (const float*)d_in[18];
  const float* pw1   = (const float*)d_in[19];
  const float* pb1   = (const float*)d_in[20];
  const float* pw2   = (const float*)d_in[21];
  const float* pb2   = (const float*)d_in[22];

  float* fw    = (float*)d_ws;
  float* raw0  = fw;                        // N*H fp32
  float* raw1  = fw + 4194304;
  float* raw2  = fw + 8388608;
  float* raw3  = fw + 12582912;
  float* aug   = fw + 16777216;             // 4096*256
  float* pX    = fw + 17825792;             // 4096*128
  float* pY    = fw + 18350080;
  float* pZ    = fw + 18874368;
  float* z8    = fw + 19398656;             // N*8
  float* invdeg= fw + 19660800;             // N
  float* bnsc  = fw + 19693568;             // 4*128
  float* bnsh  = fw + 19694080;
  float* part0 = fw + 19694592;             // 2*256*128
  float* partL = fw + 19760128;             // 3 * 2*512*128
  float* gsum  = fw + 20153344;             // B*H
  int*   cnt   = (int*)(fw + 20157440);     // N
  int*   fillc = cnt + NND;                 // N
  int*   rowp  = fillc + NND;               // N+1
  int*   csr   = rowp + NND + 1;            // E
  unsigned short* us = (unsigned short*)(fw + 20600000);
  unsigned short* zHi  = us;                // N*H bf16
  unsigned short* zLo  = us + 4194304;
  unsigned short* tHi  = us + 8388608;
  unsigned short* tLo  = us + 12582912;
  unsigned short* WThi = us + 16777216;     // 7*128*128
  unsigned short* WTlo = us + 16891904;
  float* raws[4] = {raw0, raw1, raw2, raw3};

  const int* src = ei;
  const int* dst = ei + NE;

  hipLaunchKernelGGL(k_zero, dim3(2048), dim3(256), 0, stream, (float4*)d_out, out_size/4);
  hipMemsetAsync(cnt, 0, (size_t)(2*NND)*4, stream);   // cnt, fillc
  hipLaunchKernelGGL(k_wsplit, dim3(8,7), dim3(256), 0, stream, g0w2, gw1, gw2, WThi, WTlo);

  hipLaunchKernelGGL(k_count, dim3(NE/256), dim3(256), 0, stream, dst, cnt);
  hipLaunchKernelGGL(k_scan, dim3(1), dim3(1024), 0, stream, cnt, rowp, invdeg);
  hipLaunchKernelGGL(k_fill, dim3(NE/256), dim3(256), 0, stream, src, dst, rowp, fillc, csr);

  // layer 0
  hipLaunchKernelGGL(k_agg8, dim3(NND/256), dim3(256), 0, stream, x, rowp, csr, invdeg, z8);
  hipLaunchKernelGGL(k_gemm8, dim3(NND*HD/256), dim3(256), 0, stream, z8, g0w1, g0b1, tHi, tLo);
  hipLaunchKernelGGL(k_mgemm1, dim3(NBLK), dim3(256), 0, stream, tHi, tLo, WThi, WTlo, g0b2, raw0, part0);
  hipLaunchKernelGGL(k_bn_fin, dim3(128), dim3(256), 0, stream, part0, NBLK, bng, bnb, bnsc, bnsh);

  // layers 1..3: agg_bn -> fused double-GEMM -> bn_fin
  for (int l=0;l<3;l++){
    hipLaunchKernelGGL(k_agg_bn, dim3(NND), dim3(128), 0, stream, raws[l], rowp, csr, invdeg,
                       bnsc + l*128, bnsh + l*128, zHi, zLo);
    hipLaunchKernelGGL(k_glayer, dim3(GBLK), dim3(256), 0, stream, zHi, zLo,
                       WThi + (1+l)*16384, WTlo + (1+l)*16384, gb1 + l*128,
                       WThi + (4+l)*16384, WTlo + (4+l)*16384, gb2 + l*128,
                       raws[l+1], partL + l*(2*GBLK*HD));
    hipLaunchKernelGGL(k_bn_fin, dim3(128), dim3(256), 0, stream, partL + l*(2*GBLK*HD), GBLK,
                       bng + (l+1)*128, bnb + (l+1)*128, bnsc + (l+1)*128, bnsh + (l+1)*128);
  }

  // gpool from part colsums; npool on the fly in build_aug
  hipLaunchKernelGGL(k_gpool, dim3(32), dim3(128), 0, stream, part0, partL, bnsc, bnsh, gsum);
  hipLaunchKernelGGL(k_build_aug, dim3(4096), dim3(256), 0, stream, mrows, mcols,
                     raw0, raw1, raw2, raw3, bnsc, bnsh, gsum, aug);

  hipLaunchKernelGGL((k_pol<256>), dim3(64), dim3(256), 0, stream, aug, p0w1, p0b1, p0w2, p0b2, pX);
  hipLaunchKernelGGL((k_pol<128>), dim3(64), dim3(256), 0, stream, pX, pw1, pb1, pw2, pb2, pY);
  hipLaunchKernelGGL((k_pol<128>), dim3(64), dim3(256), 0, stream, pY, pw1 + 16384, pb1 + 128, pw2 + 16384, pb2 + 128, pZ);

  hipLaunchKernelGGL(k_score, dim3(32), dim3(64), 0, stream, pZ, mrows, mcols, (float*)d_out);
}

// Round 12
// 386.453 us; speedup vs baseline: 1.1157x; 1.0190x over previous
//
#include <hip/hip_runtime.h>

#define NND 32768      // total nodes N = B*NNODES
#define NE  262144     // edges
#define HD 128
#define NPAIR 2048     // B*FEAS
#define NBLK 256       // layer-0 mgemm blocks (NND/128)
#define SQOFF 32768    // NBLK*128 (layer-0 part slot sq offset)
#define GBLK 512       // glayer blocks (NND/64)

typedef __attribute__((ext_vector_type(8))) short short8;
typedef __attribute__((ext_vector_type(4))) float f32x4;

__device__ __forceinline__ void fma4(float4& a, float s, const float4& w){
  a.x = fmaf(s, w.x, a.x);
  a.y = fmaf(s, w.y, a.y);
  a.z = fmaf(s, w.z, a.z);
  a.w = fmaf(s, w.w, a.w);
}

__device__ __forceinline__ unsigned short bf16rne(float x){
  unsigned int u = __float_as_uint(x);
  unsigned int r = u + 0x7FFFu + ((u >> 16) & 1u);
  return (unsigned short)(r >> 16);
}
__device__ __forceinline__ float bf16tof(unsigned short h){
  return __uint_as_float(((unsigned int)h) << 16);
}

// ---------------- init: zero d_out (0..2047) + wsplit (2048..2103) + zero cnt/fillc (2104..2111) ----------------
__global__ __launch_bounds__(256) void k_init(float4* __restrict__ out4, int n4,
                                              float4* __restrict__ meta4, int m4,
                                              const float* __restrict__ g0w2, const float* __restrict__ gw1,
                                              const float* __restrict__ gw2, unsigned short* __restrict__ WThi,
                                              unsigned short* __restrict__ WTlo){
  __shared__ float tile[16*129];
  int bid = blockIdx.x;
  int t = threadIdx.x;
  if (bid < 2048){
    float4 z = make_float4(0.f,0.f,0.f,0.f);
    for (int i = bid*256 + t; i < n4; i += 2048*256) out4[i] = z;
  } else if (bid < 2104){
    int q = bid - 2048;
    int mat = q >> 3, kblk = q & 7;
    int k0 = kblk * 16;
    const float* W = (mat == 0) ? g0w2 : ((mat < 4) ? (gw1 + (mat-1)*16384) : (gw2 + (mat-4)*16384));
    {
      int kk = t >> 4, n0 = (t & 15) * 8;
      float4 v0 = *(const float4*)&W[(size_t)(k0+kk)*HD + n0];
      float4 v1 = *(const float4*)&W[(size_t)(k0+kk)*HD + n0 + 4];
      tile[kk*129 + n0+0] = v0.x; tile[kk*129 + n0+1] = v0.y;
      tile[kk*129 + n0+2] = v0.z; tile[kk*129 + n0+3] = v0.w;
      tile[kk*129 + n0+4] = v1.x; tile[kk*129 + n0+5] = v1.y;
      tile[kk*129 + n0+6] = v1.z; tile[kk*129 + n0+7] = v1.w;
    }
    __syncthreads();
    int n = t >> 1, koff = (t & 1) * 8;
    short8 hv, lv;
    #pragma unroll
    for (int q2=0;q2<8;q2++){
      float v = tile[(koff+q2)*129 + n];
      unsigned short h = bf16rne(v);
      hv[q2] = (short)h;
      lv[q2] = (short)bf16rne(v - bf16tof(h));
    }
    size_t o = (size_t)mat*16384 + (size_t)n*HD + k0 + koff;
    *(short8*)&WThi[o] = hv;
    *(short8*)&WTlo[o] = lv;
  } else {
    float4 z = make_float4(0.f,0.f,0.f,0.f);
    for (int i = (bid-2104)*256 + t; i < m4; i += 8*256) meta4[i] = z;
  }
}

// ---------------- CSR build ----------------
__global__ __launch_bounds__(256) void k_count(const int* __restrict__ dst, int* __restrict__ cnt){
  int e = blockIdx.x*256 + threadIdx.x;
  if (e < NE) atomicAdd(&cnt[dst[e]], 1);
}

__global__ __launch_bounds__(1024) void k_scan(const int* __restrict__ cnt, int* __restrict__ rowp,
                                               float* __restrict__ invdeg){
  __shared__ int part[1024];
  int t = threadIdx.x;
  int base = t*32;
  int local[32];
  int s = 0;
  #pragma unroll
  for (int j=0;j<32;j++){ local[j] = s; s += cnt[base+j]; }
  part[t] = s;
  __syncthreads();
  for (int d=1; d<1024; d<<=1){
    int v = (t>=d) ? part[t-d] : 0;
    __syncthreads();
    part[t] += v;
    __syncthreads();
  }
  int off = (t==0) ? 0 : part[t-1];
  #pragma unroll
  for (int j=0;j<32;j++){
    rowp[base+j] = off + local[j];
    int c = cnt[base+j];
    invdeg[base+j] = 1.0f / (float)(c > 0 ? c : 1);
  }
  if (t == 1023) rowp[NND] = off + s;
}

__global__ __launch_bounds__(256) void k_fill(const int* __restrict__ src, const int* __restrict__ dst,
                                              const int* __restrict__ rowp, int* __restrict__ fillc,
                                              int* __restrict__ csr){
  int e = blockIdx.x*256 + threadIdx.x;
  if (e < NE){
    int d = dst[e];
    int p = atomicAdd(&fillc[d], 1);
    csr[rowp[d] + p] = src[e];
  }
}

// ---------------- layer 0 fused: agg(IN=8, 1 node/thread) + [256x8]@[8x128] + bias + ReLU -> bf16 hi/lo ----------------
__global__ __launch_bounds__(256) void k_l0f(const float* __restrict__ x, const int* __restrict__ rowp,
                                             const int* __restrict__ csr, const float* __restrict__ invdeg,
                                             const float* __restrict__ W, const float* __restrict__ bias,
                                             unsigned short* __restrict__ Ch, unsigned short* __restrict__ Cl){
  __shared__ float zs[256*9];
  __shared__ float Ws[8*HD];
  __shared__ float bs[HD];
  int tid = threadIdx.x;
  int n0 = blockIdx.x * 256;
  for (int u=tid; u<8*HD; u+=256) Ws[u] = W[u];
  if (tid < HD) bs[tid] = bias[tid];
  // gather phase: one node per thread (agg8-proven shape)
  {
    int i = n0 + tid;
    float s[8] = {0,0,0,0,0,0,0,0};
    int a = rowp[i], bnd = rowp[i+1];
    for (int k=a;k<bnd;k++){
      int j = csr[k];
      const float4* p = (const float4*)&x[(size_t)j*8];
      float4 u0 = p[0], u1 = p[1];
      s[0]+=u0.x; s[1]+=u0.y; s[2]+=u0.z; s[3]+=u0.w;
      s[4]+=u1.x; s[5]+=u1.y; s[6]+=u1.z; s[7]+=u1.w;
    }
    float iv = invdeg[i];
    const float4* xp = (const float4*)&x[(size_t)i*8];
    float4 x0 = xp[0], x1 = xp[1];
    zs[tid*9+0] = x0.x + s[0]*iv; zs[tid*9+1] = x0.y + s[1]*iv;
    zs[tid*9+2] = x0.z + s[2]*iv; zs[tid*9+3] = x0.w + s[3]*iv;
    zs[tid*9+4] = x1.x + s[4]*iv; zs[tid*9+5] = x1.y + s[5]*iv;
    zs[tid*9+6] = x1.z + s[6]*iv; zs[tid*9+7] = x1.w + s[7]*iv;
  }
  __syncthreads();
  // matmul phase: gemm8-proven mapping (row-pair x 128 cols per iteration)
  int half = tid >> 7;
  int c = tid & 127;
  float bc = bs[c];
  for (int r8 = 0; r8 < 256; r8 += 2){
    int rl = r8 + half;
    float s = bc;
    #pragma unroll
    for (int k=0;k<8;k++) s = fmaf(zs[rl*9+k], Ws[k*128+c], s);
    s = fmaxf(s, 0.f);
    unsigned short h = bf16rne(s);
    size_t g = (size_t)(n0 + rl)*HD + c;
    Ch[g] = h;
    Cl[g] = bf16rne(s - bf16tof(h));
  }
}

// ---------------- layer-0 MFMA GEMM (128-row, bf16x3, fp32 out + part stats) — R9-proven ----------------
__global__ __launch_bounds__(256) void k_mgemm1(const unsigned short* __restrict__ Ah, const unsigned short* __restrict__ Al,
                                                const unsigned short* __restrict__ Wh, const unsigned short* __restrict__ Wl,
                                                const float* __restrict__ bias, float* __restrict__ Cf,
                                                float* __restrict__ part){
  __shared__ unsigned short AH[128*40], AL[128*40], WH[128*40], WL[128*40];
  __shared__ float SS[256], SQ[256];
  int tid = threadIdx.x;
  int r0 = blockIdx.x * 128;
  int row = tid >> 1, half = tid & 1;
  int l = tid & 63, w = tid >> 6;
  int lane15 = l & 15, lgrp = l >> 4;
  int rw = (w >> 1) * 64, cw = (w & 1) * 64;

  f32x4 acc[4][4];
  #pragma unroll
  for (int i=0;i<4;i++)
    #pragma unroll
    for (int j=0;j<4;j++){ f32x4 z = {0.f,0.f,0.f,0.f}; acc[i][j] = z; }

  size_t abase = (size_t)(r0 + row)*HD + half*16;
  size_t wbase = (size_t)row*HD + half*16;
  float4 p0 = *(const float4*)&Ah[abase];     float4 p1 = *(const float4*)&Ah[abase+8];
  float4 p2 = *(const float4*)&Al[abase];     float4 p3 = *(const float4*)&Al[abase+8];
  float4 p4 = *(const float4*)&Wh[wbase];     float4 p5 = *(const float4*)&Wh[wbase+8];
  float4 p6 = *(const float4*)&Wl[wbase];     float4 p7 = *(const float4*)&Wl[wbase+8];

  for (int k0 = 0; k0 < 128; k0 += 32){
    __syncthreads();
    int ldst = row*40 + half*16;
    *(float4*)&AH[ldst] = p0; *(float4*)&AH[ldst+8] = p1;
    *(float4*)&AL[ldst] = p2; *(float4*)&AL[ldst+8] = p3;
    *(float4*)&WH[ldst] = p4; *(float4*)&WH[ldst+8] = p5;
    *(float4*)&WL[ldst] = p6; *(float4*)&WL[ldst+8] = p7;
    __syncthreads();
    if (k0 < 96){
      p0 = *(const float4*)&Ah[abase + k0+32]; p1 = *(const float4*)&Ah[abase + k0+40];
      p2 = *(const float4*)&Al[abase + k0+32]; p3 = *(const float4*)&Al[abase + k0+40];
      p4 = *(const float4*)&Wh[wbase + k0+32]; p5 = *(const float4*)&Wh[wbase + k0+40];
      p6 = *(const float4*)&Wl[wbase + k0+32]; p7 = *(const float4*)&Wl[wbase + k0+40];
    }
    short8 ah[4], al[4], wh[4], wl[4];
    #pragma unroll
    for (int i=0;i<4;i++){
      int ar = (rw + 16*i + lane15)*40 + lgrp*8;
      ah[i] = *(const short8*)&AH[ar];
      al[i] = *(const short8*)&AL[ar];
      int wr = (cw + 16*i + lane15)*40 + lgrp*8;
      wh[i] = *(const short8*)&WH[wr];
      wl[i] = *(const short8*)&WL[wr];
    }
    #pragma unroll
    for (int i=0;i<4;i++){
      #pragma unroll
      for (int j=0;j<4;j++){
        acc[i][j] = __builtin_amdgcn_mfma_f32_16x16x32_bf16(ah[i], wh[j], acc[i][j], 0, 0, 0);
        acc[i][j] = __builtin_amdgcn_mfma_f32_16x16x32_bf16(al[i], wh[j], acc[i][j], 0, 0, 0);
        acc[i][j] = __builtin_amdgcn_mfma_f32_16x16x32_bf16(ah[i], wl[j], acc[i][j], 0, 0, 0);
      }
    }
  }

  float bj[4], sj[4] = {0,0,0,0}, qj[4] = {0,0,0,0};
  #pragma unroll
  for (int j=0;j<4;j++) bj[j] = bias[cw + 16*j + lane15];
  #pragma unroll
  for (int i=0;i<4;i++){
    #pragma unroll
    for (int j=0;j<4;j++){
      f32x4 v = acc[i][j];
      int n = cw + 16*j + lane15;
      #pragma unroll
      for (int r=0;r<4;r++){
        float xv = fmaxf(v[r] + bj[j], 0.f);
        int m = r0 + rw + 16*i + 4*lgrp + r;
        Cf[(size_t)m*HD + n] = xv;
        sj[j] += xv;
        qj[j] = fmaf(xv, xv, qj[j]);
      }
    }
  }
  #pragma unroll
  for (int j=0;j<4;j++){
    float s = sj[j], q = qj[j];
    s += __shfl_xor(s, 16); s += __shfl_xor(s, 32);
    q += __shfl_xor(q, 16); q += __shfl_xor(q, 32);
    if (lgrp == 0){
      SS[(w>>1)*128 + cw + 16*j + lane15] = s;
      SQ[(w>>1)*128 + cw + 16*j + lane15] = q;
    }
  }
  __syncthreads();
  if (tid < HD){
    part[blockIdx.x*HD + tid] = SS[tid] + SS[128 + tid];
    part[SQOFF + blockIdx.x*HD + tid] = SQ[tid] + SQ[128 + tid];
  }
}

// ---------------- fused GIN layer (R11-proven): raw = relu( relu(z@W1+b1) @ W2 + b2 ) + part stats ----------------
__global__ __launch_bounds__(256) void k_glayer(const unsigned short* __restrict__ Ah, const unsigned short* __restrict__ Al,
                                                const unsigned short* __restrict__ W1h, const unsigned short* __restrict__ W1l,
                                                const float* __restrict__ b1,
                                                const unsigned short* __restrict__ W2h, const unsigned short* __restrict__ W2l,
                                                const float* __restrict__ b2,
                                                float* __restrict__ Cf, float* __restrict__ part){
  __shared__ unsigned short AH[64*40], AL[64*40], WH[128*40], WL[128*40];
  __shared__ unsigned short TH[64*136], TL[64*136];
  __shared__ float SS[128], SQ[128];
  int tid = threadIdx.x;
  int r0 = blockIdx.x * 64;
  int l = tid & 63, w = tid >> 6;
  int lane15 = l & 15, lgrp = l >> 4;
  int cw = w * 32;

  f32x4 acc[4][2];
  #pragma unroll
  for (int i=0;i<4;i++){
    #pragma unroll
    for (int j=0;j<2;j++){ f32x4 z = {0.f,0.f,0.f,0.f}; acc[i][j] = z; }
  }

  int arow = tid >> 2, akoff = (tid & 3) * 8;
  size_t abase = (size_t)(r0 + arow)*HD + akoff;
  int wrow = tid >> 1, whalf = (tid & 1) * 16;
  size_t wbase = (size_t)wrow*HD + whalf;
  float4 pa0 = *(const float4*)&Ah[abase];
  float4 pa1 = *(const float4*)&Al[abase];
  float4 pw0 = *(const float4*)&W1h[wbase], pw1 = *(const float4*)&W1h[wbase+8];
  float4 pw2 = *(const float4*)&W1l[wbase], pw3 = *(const float4*)&W1l[wbase+8];

  // ---- phase 1: t = relu(z @ W1 + b1) ----
  for (int k0 = 0; k0 < 128; k0 += 32){
    __syncthreads();
    *(float4*)&AH[arow*40 + akoff] = pa0;
    *(float4*)&AL[arow*40 + akoff] = pa1;
    int wd = wrow*40 + whalf;
    *(float4*)&WH[wd] = pw0; *(float4*)&WH[wd+8] = pw1;
    *(float4*)&WL[wd] = pw2; *(float4*)&WL[wd+8] = pw3;
    __syncthreads();
    if (k0 < 96){
      pa0 = *(const float4*)&Ah[abase + k0+32];
      pa1 = *(const float4*)&Al[abase + k0+32];
      pw0 = *(const float4*)&W1h[wbase + k0+32]; pw1 = *(const float4*)&W1h[wbase + k0+40];
      pw2 = *(const float4*)&W1l[wbase + k0+32]; pw3 = *(const float4*)&W1l[wbase + k0+40];
    }
    short8 ah[4], al4[4], wh[2], wl[2];
    #pragma unroll
    for (int i=0;i<4;i++){
      int ar = (16*i + lane15)*40 + lgrp*8;
      ah[i]  = *(const short8*)&AH[ar];
      al4[i] = *(const short8*)&AL[ar];
    }
    #pragma unroll
    for (int j=0;j<2;j++){
      int wr = (cw + 16*j + lane15)*40 + lgrp*8;
      wh[j] = *(const short8*)&WH[wr];
      wl[j] = *(const short8*)&WL[wr];
    }
    #pragma unroll
    for (int i=0;i<4;i++){
      #pragma unroll
      for (int j=0;j<2;j++){
        acc[i][j] = __builtin_amdgcn_mfma_f32_16x16x32_bf16(ah[i],  wh[j], acc[i][j], 0, 0, 0);
        acc[i][j] = __builtin_amdgcn_mfma_f32_16x16x32_bf16(al4[i], wh[j], acc[i][j], 0, 0, 0);
        acc[i][j] = __builtin_amdgcn_mfma_f32_16x16x32_bf16(ah[i],  wl[j], acc[i][j], 0, 0, 0);
      }
    }
  }
  {
    float bA = b1[cw + lane15], bB = b1[cw + 16 + lane15];
    #pragma unroll
    for (int i=0;i<4;i++){
      #pragma unroll
      for (int j=0;j<2;j++){
        f32x4 v = acc[i][j];
        float bb = j ? bB : bA;
        int n = cw + 16*j + lane15;
        #pragma unroll
        for (int r=0;r<4;r++){
          float xv = fmaxf(v[r] + bb, 0.f);
          int m = 16*i + 4*lgrp + r;
          unsigned short h = bf16rne(xv);
          TH[m*136 + n] = h;
          TL[m*136 + n] = bf16rne(xv - bf16tof(h));
        }
      }
    }
  }
  // ---- phase 2: raw = relu(t @ W2 + b2) ----
  #pragma unroll
  for (int i=0;i<4;i++){
    #pragma unroll
    for (int j=0;j<2;j++){ f32x4 z = {0.f,0.f,0.f,0.f}; acc[i][j] = z; }
  }
  pw0 = *(const float4*)&W2h[wbase]; pw1 = *(const float4*)&W2h[wbase+8];
  pw2 = *(const float4*)&W2l[wbase]; pw3 = *(const float4*)&W2l[wbase+8];
  for (int k0 = 0; k0 < 128; k0 += 32){
    __syncthreads();
    int wd = wrow*40 + whalf;
    *(float4*)&WH[wd] = pw0; *(float4*)&WH[wd+8] = pw1;
    *(float4*)&WL[wd] = pw2; *(float4*)&WL[wd+8] = pw3;
    __syncthreads();
    if (k0 < 96){
      pw0 = *(const float4*)&W2h[wbase + k0+32]; pw1 = *(const float4*)&W2h[wbase + k0+40];
      pw2 = *(const float4*)&W2l[wbase + k0+32]; pw3 = *(const float4*)&W2l[wbase + k0+40];
    }
    short8 ah[4], al4[4], wh[2], wl[2];
    #pragma unroll
    for (int i=0;i<4;i++){
      int ar = (16*i + lane15)*136 + k0 + lgrp*8;
      ah[i]  = *(const short8*)&TH[ar];
      al4[i] = *(const short8*)&TL[ar];
    }
    #pragma unroll
    for (int j=0;j<2;j++){
      int wr = (cw + 16*j + lane15)*40 + lgrp*8;
      wh[j] = *(const short8*)&WH[wr];
      wl[j] = *(const short8*)&WL[wr];
    }
    #pragma unroll
    for (int i=0;i<4;i++){
      #pragma unroll
      for (int j=0;j<2;j++){
        acc[i][j] = __builtin_amdgcn_mfma_f32_16x16x32_bf16(ah[i],  wh[j], acc[i][j], 0, 0, 0);
        acc[i][j] = __builtin_amdgcn_mfma_f32_16x16x32_bf16(al4[i], wh[j], acc[i][j], 0, 0, 0);
        acc[i][j] = __builtin_amdgcn_mfma_f32_16x16x32_bf16(ah[i],  wl[j], acc[i][j], 0, 0, 0);
      }
    }
  }
  {
    float bA = b2[cw + lane15], bB = b2[cw + 16 + lane15];
    float s0 = 0.f, s1 = 0.f, q0 = 0.f, q1 = 0.f;
    #pragma unroll
    for (int i=0;i<4;i++){
      #pragma unroll
      for (int j=0;j<2;j++){
        f32x4 v = acc[i][j];
        float bb = j ? bB : bA;
        int n = cw + 16*j + lane15;
        #pragma unroll
        for (int r=0;r<4;r++){
          float xv = fmaxf(v[r] + bb, 0.f);
          int m = r0 + 16*i + 4*lgrp + r;
          Cf[(size_t)m*HD + n] = xv;
          if (j){ s1 += xv; q1 = fmaf(xv, xv, q1); }
          else  { s0 += xv; q0 = fmaf(xv, xv, q0); }
        }
      }
    }
    s0 += __shfl_xor(s0, 16); s0 += __shfl_xor(s0, 32);
    s1 += __shfl_xor(s1, 16); s1 += __shfl_xor(s1, 32);
    q0 += __shfl_xor(q0, 16); q0 += __shfl_xor(q0, 32);
    q1 += __shfl_xor(q1, 16); q1 += __shfl_xor(q1, 32);
    if (lgrp == 0){
      SS[cw + lane15] = s0;      SS[cw + 16 + lane15] = s1;
      SQ[cw + lane15] = q0;      SQ[cw + 16 + lane15] = q1;
    }
  }
  __syncthreads();
  if (tid < HD){
    part[blockIdx.x*HD + tid] = SS[tid];
    part[GBLK*HD + blockIdx.x*HD + tid] = SQ[tid];
  }
}

// ---------------- BN finalize: one block per feature, generic block count ----------------
__global__ __launch_bounds__(256) void k_bn_fin(const float* __restrict__ part, int nblk,
                                                const float* __restrict__ gamma, const float* __restrict__ beta,
                                                float* __restrict__ scale, float* __restrict__ shift){
  __shared__ float rs[256];
  __shared__ float rq[256];
  int f = blockIdx.x, t = threadIdx.x;
  float s = 0.f, q = 0.f;
  for (int b = t; b < nblk; b += 256){
    s += part[b*HD + f];
    q += part[nblk*HD + b*HD + f];
  }
  rs[t] = s; rq[t] = q;
  __syncthreads();
  for (int d=128; d>0; d>>=1){
    if (t < d){ rs[t] += rs[t+d]; rq[t] += rq[t+d]; }
    __syncthreads();
  }
  if (t == 0){
    float mu  = rs[0] * (1.0f/NND);
    float var = rq[0] * (1.0f/NND) - mu*mu;
    float sc  = gamma[f] * rsqrtf(var + 1e-5f);
    scale[f] = sc;
    shift[f] = beta[f] - mu*sc;
  }
}

// ---------------- fused: BN-apply (folded) + mean-aggregate -> bf16 hi/lo z ----------------
__global__ __launch_bounds__(128) void k_agg_bn(const float* __restrict__ raw, const int* __restrict__ rowp,
                                                const int* __restrict__ csr, const float* __restrict__ invdeg,
                                                const float* __restrict__ scale, const float* __restrict__ shift,
                                                unsigned short* __restrict__ zh, unsigned short* __restrict__ zl){
  int i = blockIdx.x;
  int f = threadIdx.x;
  int a = rowp[i], bnd = rowp[i+1];
  float s = 0.f;
  for (int k = a; k < bnd; k++) s += raw[(size_t)csr[k]*HD + f];
  float sc = scale[f], sh = shift[f];
  size_t idx = (size_t)i*HD + f;
  float vi = fmaf(raw[idx], sc, sh);
  float zz = vi + fmaf(invdeg[i]*sc, s, (bnd > a) ? sh : 0.f);
  unsigned short h = bf16rne(zz);
  zh[idx] = h;
  zl[idx] = bf16rne(zz - bf16tof(h));
}

// ---------------- gpool from per-block part colsums (layer0: 8 blocks/batch; layers1-3: 16) ----------------
__global__ __launch_bounds__(128) void k_gpool(const float* __restrict__ part0, const float* __restrict__ partL,
                                               const float* __restrict__ bnsc, const float* __restrict__ bnsh,
                                               float* __restrict__ gsum){
  int b = blockIdx.x, f = threadIdx.x;
  float g;
  {
    float s = 0.f;
    #pragma unroll
    for (int t=0;t<8;t++) s += part0[(b*8 + t)*HD + f];
    g = fmaf(bnsc[f], s, 1024.0f*bnsh[f]);
  }
  #pragma unroll
  for (int l=1;l<4;l++){
    float s = 0.f;
    #pragma unroll
    for (int t=0;t<16;t++) s += partL[(l-1)*2*GBLK*HD + (b*16 + t)*HD + f];
    g += fmaf(bnsc[l*128+f], s, 1024.0f*bnsh[l*128+f]);
  }
  gsum[b*HD + f] = g;
}

// ---------------- build aug rows (npool on the fly from raw0..raw3) ----------------
__global__ __launch_bounds__(256) void k_build_aug(const int* __restrict__ mrows, const int* __restrict__ mcols,
                                                   const float* __restrict__ raw0, const float* __restrict__ raw1,
                                                   const float* __restrict__ raw2, const float* __restrict__ raw3,
                                                   const float* __restrict__ bnsc, const float* __restrict__ bnsh,
                                                   const float* __restrict__ gsum, float* __restrict__ aug){
  int idx = blockIdx.x;     // 0..4095: first 2048 = row nodes, next 2048 = col nodes
  int t = threadIdx.x;
  int j = idx & 2047;
  int rg = mrows[j];
  int b = rg >> 10;
  int g = (idx >= 2048) ? ((b << 10) | mcols[j]) : rg;
  float v;
  if (t < 128){
    size_t o = (size_t)g*HD + t;
    v = fmaf(bnsc[t],     raw0[o], bnsh[t]);
    v = fmaf(bnsc[128+t], raw1[o], v + bnsh[128+t]);
    v = fmaf(bnsc[256+t], raw2[o], v + bnsh[256+t]);
    v = fmaf(bnsc[384+t], raw3[o], v + bnsh[384+t]);
  } else {
    v = gsum[b*HD + (t-128)] * (1.0f/1024.0f);
  }
  aug[(size_t)idx*256 + t] = v;
}

// fused policy layer: C = tanh(A@W1+b1)@W2+b2.  64-row tile (proven).
template<int K1>
__global__ __launch_bounds__(256) void k_pol(const float* __restrict__ A, const float* __restrict__ W1,
                                             const float* __restrict__ b1, const float* __restrict__ W2,
                                             const float* __restrict__ b2, float* __restrict__ C){
  __shared__ float S1[32*128 + 64*36];
  __shared__ float T[64*132];
  int tid = threadIdx.x;
  int r0 = blockIdx.x * 64;
  int tc = tid & 15, rg = tid >> 4;
  int c0 = tc * 4;
  float4 acc0[4], acc1[4];
  #pragma unroll
  for (int j=0;j<4;j++){ acc0[j] = make_float4(0,0,0,0); acc1[j] = make_float4(0,0,0,0); }
  for (int k0 = 0; k0 < K1; k0 += 32){
    __syncthreads();
    #pragma unroll
    for (int u=0;u<4;u++){
      int e = tid + u*256;
      *(float4*)&S1[(e>>5)*HD + ((e&31)<<2)] = *(const float4*)&W1[(size_t)(k0 + (e>>5))*HD + ((e&31)<<2)];
    }
    #pragma unroll
    for (int u=0;u<2;u++){
      int e = tid + u*256;
      *(float4*)&S1[4096 + (e>>3)*36 + ((e&7)<<2)] = *(const float4*)&A[(size_t)(r0 + (e>>3))*K1 + k0 + ((e&7)<<2)];
    }
    __syncthreads();
    #pragma unroll
    for (int kk=0; kk<32; kk+=4){
      float4 w0[4], w1[4];
      #pragma unroll
      for (int q=0;q<4;q++){
        w0[q] = *(const float4*)&S1[(kk+q)*HD + c0];
        w1[q] = *(const float4*)&S1[(kk+q)*HD + c0 + 64];
      }
      #pragma unroll
      for (int j=0;j<4;j++){
        float4 av = *(const float4*)&S1[4096 + (rg+16*j)*36 + kk];
        fma4(acc0[j], av.x, w0[0]); fma4(acc1[j], av.x, w1[0]);
        fma4(acc0[j], av.y, w0[1]); fma4(acc1[j], av.y, w1[1]);
        fma4(acc0[j], av.z, w0[2]); fma4(acc1[j], av.z, w1[2]);
        fma4(acc0[j], av.w, w0[3]); fma4(acc1[j], av.w, w1[3]);
      }
    }
  }
  {
    float4 bA = *(const float4*)&b1[c0];
    float4 bB = *(const float4*)&b1[c0+64];
    #pragma unroll
    for (int j=0;j<4;j++){
      int r = rg + 16*j;
      float4 v0 = acc0[j], v1 = acc1[j];
      v0.x = tanhf(v0.x + bA.x); v0.y = tanhf(v0.y + bA.y);
      v0.z = tanhf(v0.z + bA.z); v0.w = tanhf(v0.w + bA.w);
      v1.x = tanhf(v1.x + bB.x); v1.y = tanhf(v1.y + bB.y);
      v1.z = tanhf(v1.z + bB.z); v1.w = tanhf(v1.w + bB.w);
      *(float4*)&T[r*132 + c0] = v0;
      *(float4*)&T[r*132 + c0 + 64] = v1;
    }
  }
  float4 d0[4], d1[4];
  #pragma unroll
  for (int j=0;j<4;j++){ d0[j] = make_float4(0,0,0,0); d1[j] = make_float4(0,0,0,0); }
  for (int k0 = 0; k0 < HD; k0 += 32){
    __syncthreads();
    #pragma unroll
    for (int u=0;u<4;u++){
      int e = tid + u*256;
      *(float4*)&S1[(e>>5)*HD + ((e&31)<<2)] = *(const float4*)&W2[(size_t)(k0 + (e>>5))*HD + ((e&31)<<2)];
    }
    __syncthreads();
    #pragma unroll
    for (int kk=0; kk<32; kk+=4){
      float4 w0[4], w1[4];
      #pragma unroll
      for (int q=0;q<4;q++){
        w0[q] = *(const float4*)&S1[(kk+q)*HD + c0];
        w1[q] = *(const float4*)&S1[(kk+q)*HD + c0 + 64];
      }
      #pragma unroll
      for (int j=0;j<4;j++){
        float4 av = *(const float4*)&T[(rg+16*j)*132 + k0 + kk];
        fma4(d0[j], av.x, w0[0]); fma4(d1[j], av.x, w1[0]);
        fma4(d0[j], av.y, w0[1]); fma4(d1[j], av.y, w1[1]);
        fma4(d0[j], av.z, w0[2]); fma4(d1[j], av.z, w1[2]);
        fma4(d0[j], av.w, w0[3]); fma4(d1[j], av.w, w1[3]);
      }
    }
  }
  float4 bA = *(const float4*)&b2[c0];
  float4 bB = *(const float4*)&b2[c0+64];
  #pragma unroll
  for (int j=0;j<4;j++){
    int row = r0 + rg + 16*j;
    float4 v0 = d0[j], v1 = d1[j];
    v0.x += bA.x; v0.y += bA.y; v0.z += bA.z; v0.w += bA.w;
    v1.x += bB.x; v1.y += bB.y; v1.z += bB.z; v1.w += bB.w;
    *(float4*)&C[(size_t)row*HD + c0] = v0;
    *(float4*)&C[(size_t)row*HD + c0 + 64] = v1;
  }
}

// score + per-batch sparse softmax (dedup of repeated cells) + scatter
__global__ __launch_bounds__(64) void k_score(const float* __restrict__ Z, const int* __restrict__ mrows,
                                              const int* __restrict__ mcols, float* __restrict__ out){
  __shared__ int rr[64]; __shared__ int cc[64]; __shared__ float red[64];
  int b = blockIdx.x, f = threadIdx.x;
  int i = b*64 + f;
  int rg = mrows[i];
  int row = rg & 1023;
  int col = mcols[i];
  const float4* zr = (const float4*)&Z[(size_t)i*HD];
  const float4* zc = (const float4*)&Z[(size_t)(NPAIR + i)*HD];
  float s = 0.f;
  #pragma unroll
  for (int k=0;k<32;k++){
    float4 a = zr[k], c = zc[k];
    s = fmaf(a.x,c.x, fmaf(a.y,c.y, fmaf(a.z,c.z, fmaf(a.w,c.w, s))));
  }
  rr[f]=row; cc[f]=col; red[f]=s;
  __syncthreads();
  for (int d=32; d>0; d>>=1){
    if (f<d) red[f] = fmaxf(red[f], red[f+d]);
    __syncthreads();
  }
  float m = red[0];
  __syncthreads();
  bool first = true;
  for (int j=0;j<f;j++) if (rr[j]==row && cc[j]==col) first = false;
  float e = expf(s - m);
  red[f] = first ? e : 0.0f;
  __syncthreads();
  for (int d=32; d>0; d>>=1){
    if (f<d) red[f] += red[f+d];
    __syncthreads();
  }
  float denom = red[0];
  out[(size_t)b*1048576 + row*1024 + col] = e / denom;
}

extern "C" void kernel_launch(void* const* d_in, const int* in_sizes, int n_in,
                              void* d_out, int out_size, void* d_ws, size_t ws_size,
                              hipStream_t stream){
  const float* x     = (const float*)d_in[0];
  const int*   ei    = (const int*)d_in[1];
  const int*   mrows = (const int*)d_in[3];
  const int*   mcols = (const int*)d_in[4];
  const float* g0w1  = (const float*)d_in[5];
  const float* g0b1  = (const float*)d_in[6];
  const float* g0w2  = (const float*)d_in[7];
  const float* g0b2  = (const float*)d_in[8];
  const float* gw1   = (const float*)d_in[9];
  const float* gb1   = (const float*)d_in[10];
  const float* gw2   = (const float*)d_in[11];
  const float* gb2   = (const float*)d_in[12];
  const float* bng   = (const float*)d_in[13];
  const float* bnb   = (const float*)d_in[14];
  const float* p0w1  = (const float*)d_in[15];
  const float* p0b1  = (const float*)d_in[16];
  const float* p0w2  = (const float*)d_in[17];
  const float* p0b2  = (const float*)d_in[18];
  const float* pw1   = (const float*)d_in[19];
  const float* pb1   = (const float*)d_in[20];
  const float* pw2   = (const float*)d_in[21];
  const float* pb2   = (const float*)d_in[22];

  float* fw    = (float*)d_ws;
  float* raw0  = fw;                        // N*H fp32
  float* raw1  = fw + 4194304;
  float* raw2  = fw + 8388608;
  float* raw3  = fw + 12582912;
  float* aug   = fw + 16777216;             // 4096*256
  float* pX    = fw + 17825792;             // 4096*128
  float* pY    = fw + 18350080;
  float* pZ    = fw + 18874368;
  float* invdeg= fw + 19660800;             // N
  float* bnsc  = fw + 19693568;             // 4*128
  float* bnsh  = fw + 19694080;
  float* part0 = fw + 19694592;             // 2*256*128
  float* partL = fw + 19760128;             // 3 * 2*512*128
  float* gsum  = fw + 20153344;             // B*H
  int*   cnt   = (int*)(fw + 20157440);     // N  (meta region start)
  int*   fillc = cnt + NND;                 // N
  int*   rowp  = fillc + NND;               // N+1
  int*   csr   = rowp + NND + 1;            // E
  unsigned short* us = (unsigned short*)(fw + 20600000);
  unsigned short* zHi  = us;                // N*H bf16
  unsigned short* zLo  = us + 4194304;
  unsigned short* tHi  = us + 8388608;
  unsigned short* tLo  = us + 12582912;
  unsigned short* WThi = us + 16777216;     // 7*128*128
  unsigned short* WTlo = us + 16891904;
  float* raws[4] = {raw0, raw1, raw2, raw3};

  const int* src = ei;
  const int* dst = ei + NE;

  const int META4 = (2*NND) / 4;   // cnt + fillc as float4 count

  hipLaunchKernelGGL(k_init, dim3(2112), dim3(256), 0, stream, (float4*)d_out, out_size/4,
                     (float4*)cnt, META4, g0w2, gw1, gw2, WThi, WTlo);

  hipLaunchKernelGGL(k_count, dim3(NE/256), dim3(256), 0, stream, dst, cnt);
  hipLaunchKernelGGL(k_scan, dim3(1), dim3(1024), 0, stream, cnt, rowp, invdeg);
  hipLaunchKernelGGL(k_fill, dim3(NE/256), dim3(256), 0, stream, src, dst, rowp, fillc, csr);

  // layer 0 (fused agg + 8->128 matmul, then MFMA GEMM with stats)
  hipLaunchKernelGGL(k_l0f, dim3(NND/256), dim3(256), 0, stream, x, rowp, csr, invdeg, g0w1, g0b1, tHi, tLo);
  hipLaunchKernelGGL(k_mgemm1, dim3(NBLK), dim3(256), 0, stream, tHi, tLo, WThi, WTlo, g0b2, raw0, part0);
  hipLaunchKernelGGL(k_bn_fin, dim3(128), dim3(256), 0, stream, part0, NBLK, bng, bnb, bnsc, bnsh);

  // layers 1..3: agg_bn -> fused double-GEMM -> bn_fin
  for (int l=0;l<3;l++){
    hipLaunchKernelGGL(k_agg_bn, dim3(NND), dim3(128), 0, stream, raws[l], rowp, csr, invdeg,
                       bnsc + l*128, bnsh + l*128, zHi, zLo);
    hipLaunchKernelGGL(k_glayer, dim3(GBLK), dim3(256), 0, stream, zHi, zLo,
                       WThi + (1+l)*16384, WTlo + (1+l)*16384, gb1 + l*128,
                       WThi + (4+l)*16384, WTlo + (4+l)*16384, gb2 + l*128,
                       raws[l+1], partL + l*(2*GBLK*HD));
    hipLaunchKernelGGL(k_bn_fin, dim3(128), dim3(256), 0, stream, partL + l*(2*GBLK*HD), GBLK,
                       bng + (l+1)*128, bnb + (l+1)*128, bnsc + (l+1)*128, bnsh + (l+1)*128);
  }

  // gpool from part colsums; npool on the fly in build_aug
  hipLaunchKernelGGL(k_gpool, dim3(32), dim3(128), 0, stream, part0, partL, bnsc, bnsh, gsum);
  hipLaunchKernelGGL(k_build_aug, dim3(4096), dim3(256), 0, stream, mrows, mcols,
                     raw0, raw1, raw2, raw3, bnsc, bnsh, gsum, aug);

  hipLaunchKernelGGL((k_pol<256>), dim3(64), dim3(256), 0, stream, aug, p0w1, p0b1, p0w2, p0b2, pX);
  hipLaunchKernelGGL((k_pol<128>), dim3(64), dim3(256), 0, stream, pX, pw1, pb1, pw2, pb2, pY);
  hipLaunchKernelGGL((k_pol<128>), dim3(64), dim3(256), 0, stream, pY, pw1 + 16384, pb1 + 128, pw2 + 16384, pb2 + 128, pZ);

  hipLaunchKernelGGL(k_score, dim3(32), dim3(64), 0, stream, pZ, mrows, mcols, (float*)d_out);
}